// Round 6
// baseline (930.237 us; speedup 1.0000x reference)
//
#include <hip/hip_runtime.h>
#include <hip/hip_bf16.h>
#include <hip/hip_runtime_api.h>

// Problem constants
#define NROWS 8192
#define HID 128
#define OUTC 40

typedef unsigned short ushort_t;
typedef __attribute__((ext_vector_type(8))) short bf16x8;
typedef __attribute__((ext_vector_type(4))) short short4v;
typedef __attribute__((ext_vector_type(4))) float f32x4;

// f32 -> bf16 RNE
__device__ __forceinline__ short f2bf(float f) {
    unsigned int u = __float_as_uint(f);
    unsigned int r = (u + 0x7FFFu + ((u >> 16) & 1u)) >> 16;
    return (short)r;
}
__device__ __forceinline__ float bf2f(ushort_t b) {
    return __uint_as_float(((unsigned int)b) << 16);
}

__device__ __forceinline__ float exp2_fast(float x) {
#if __has_builtin(__builtin_amdgcn_exp2f)
    return __builtin_amdgcn_exp2f(x);
#else
    return exp2f(x);
#endif
}

// bias (log2 domain): r = scale2/d ; d==0 -> inf -> 0 (sp is finite randint 0..10)
__device__ __forceinline__ float bias_of(float f, float scale2) {
    float r = scale2 * __builtin_amdgcn_rcpf(f);
    bool bad = (__float_as_uint(r) & 0x7F800000u) == 0x7F800000u;
    return bad ? 0.f : r;
}

// ---------- K0: one-time f32 -> bf16 conversion of x and all weights ----------
__global__ __launch_bounds__(256) void k_prep(const float* __restrict__ x,
                                              const float* __restrict__ Wi,
                                              const float* __restrict__ Wp,
                                              const float* __restrict__ Wo,
                                              const float* __restrict__ Wout,
                                              ushort_t* __restrict__ xb,
                                              ushort_t* __restrict__ wib,
                                              ushort_t* __restrict__ wpb,
                                              ushort_t* __restrict__ wob,
                                              ushort_t* __restrict__ woutb) {
    int rb = blockIdx.x;
    const float* src; ushort_t* dst; int n, base;
    if (rb < 512)      { src = x;    dst = xb;    n = NROWS * 128; base = rb; }
    else if (rb < 520) { src = Wi;   dst = wib;   n = 128 * 128;   base = rb - 512; }
    else if (rb < 544) { src = Wp;   dst = wpb;   n = 384 * 128;   base = rb - 520; }
    else if (rb < 552) { src = Wo;   dst = wob;   n = 128 * 128;   base = rb - 544; }
    else               { src = Wout; dst = woutb; n = OUTC * 128;  base = rb - 552; }
    int i0 = base * 2048 + threadIdx.x * 8;
    if (i0 < n) {
        float4 a = *(const float4*)(src + i0);
        float4 b = *(const float4*)(src + i0 + 4);
        short4v s0 = {f2bf(a.x), f2bf(a.y), f2bf(a.z), f2bf(a.w)};
        short4v s1 = {f2bf(b.x), f2bf(b.y), f2bf(b.z), f2bf(b.w)};
        *(short4v*)(dst + i0) = s0;
        *(short4v*)(dst + i0 + 4) = s1;
    }
}

// ---------- K1: fused h = x@Wi^T+bi -> qkv = h@Wp^T+bp (all-bf16 operands) ----------
// Emits: hbf (residual), qkb[token][256] (q|k, q pre-scaled by log2e/sqrt(hd)), vTg[d][token]
__global__ __launch_bounds__(256) void k_qkv_fused(const ushort_t* __restrict__ xb,
                                                   const ushort_t* __restrict__ wib,
                                                   const float* __restrict__ bi,
                                                   const ushort_t* __restrict__ wpb,
                                                   const float* __restrict__ bp,
                                                   ushort_t* __restrict__ hbf,
                                                   ushort_t* __restrict__ qkb,
                                                   ushort_t* __restrict__ vTg) {
    __shared__ __align__(16) ushort_t h_s[32][136];
    const int w = threadIdx.x >> 6, lane = threadIdx.x & 63;
    const int l15 = lane & 15, quad = lane >> 4;
    const int r0 = blockIdx.x * 32;

    // phase 1: h rows r0..r0+31 (wave w owns output cols w*32..w*32+31)
    {
        const int n0 = w * 32;
        bf16x8 af[2][4], bfr[2][4];
#pragma unroll
        for (int mt = 0; mt < 2; ++mt)
#pragma unroll
            for (int kf = 0; kf < 4; ++kf)
                af[mt][kf] = *(const bf16x8*)(xb + (size_t)(r0 + mt * 16 + l15) * 128 + kf * 32 + quad * 8);
#pragma unroll
        for (int nt = 0; nt < 2; ++nt)
#pragma unroll
            for (int kf = 0; kf < 4; ++kf)
                bfr[nt][kf] = *(const bf16x8*)(wib + (size_t)(n0 + nt * 16 + l15) * 128 + kf * 32 + quad * 8);
#pragma unroll
        for (int mt = 0; mt < 2; ++mt)
#pragma unroll
            for (int nt = 0; nt < 2; ++nt) {
                float bias = bi[n0 + nt * 16 + l15];
                f32x4 c = {bias, bias, bias, bias};
#pragma unroll
                for (int kf = 0; kf < 4; ++kf)
                    c = __builtin_amdgcn_mfma_f32_16x16x32_bf16(af[mt][kf], bfr[nt][kf], c, 0, 0, 0);
                int col = n0 + nt * 16 + l15;
#pragma unroll
                for (int r = 0; r < 4; ++r) {
                    int row = mt * 16 + quad * 4 + r;
                    short hv = f2bf(c[r]);
                    h_s[row][col] = (ushort_t)hv;
                    hbf[(size_t)(r0 + row) * 128 + col] = (ushort_t)hv;
                }
            }
    }
    __syncthreads();
    // phase 2: qkv (wave w owns output cols w*96..w*96+95)
    bf16x8 af2[2][4];
#pragma unroll
    for (int mt = 0; mt < 2; ++mt)
#pragma unroll
        for (int kf = 0; kf < 4; ++kf)
            af2[mt][kf] = *(const bf16x8*)&h_s[mt * 16 + l15][kf * 32 + quad * 8];
    // q scale = log2e / sqrt(32)
    const float QS = 0.25503482459918643f;
#pragma unroll
    for (int nt = 0; nt < 6; ++nt) {
        const int n0 = w * 96 + nt * 16;
        bf16x8 bfr[4];
#pragma unroll
        for (int kf = 0; kf < 4; ++kf)
            bfr[kf] = *(const bf16x8*)(wpb + (size_t)(n0 + l15) * 128 + kf * 32 + quad * 8);
        float bias = bp[n0 + l15];
        float sc = (n0 < 128) ? QS : 1.0f;
#pragma unroll
        for (int mt = 0; mt < 2; ++mt) {
            f32x4 c = {bias, bias, bias, bias};
#pragma unroll
            for (int kf = 0; kf < 4; ++kf)
                c = __builtin_amdgcn_mfma_f32_16x16x32_bf16(af2[mt][kf], bfr[kf], c, 0, 0, 0);
            if (n0 < 256) {  // q or k -> token-major
#pragma unroll
                for (int r = 0; r < 4; ++r)
                    qkb[(size_t)(r0 + mt * 16 + quad * 4 + r) * 256 + n0 + l15] =
                        (ushort_t)f2bf(c[r] * sc);
            } else {  // v -> transposed [d][token], packed b64
                int vd = n0 + l15 - 256;
                short4v pk = {f2bf(c[0]), f2bf(c[1]), f2bf(c[2]), f2bf(c[3])};
                *(short4v*)&vTg[(size_t)vd * NROWS + r0 + mt * 16 + quad * 4] = pk;
            }
        }
    }
}

// ---------- K2: flash attention partials. 1 wave/block = (q-tile, head, key-half) ----------
// No barriers, no K/V LDS: MFMA fragments loaded directly from global (L2-resident).
// S^T = K.Q^T (C: col=l15=q, row=quad*4+r=key); O^T = V^T.P^T. Log2-domain softmax.
__global__ __launch_bounds__(64, 4) void k_attn(const ushort_t* __restrict__ qkb,
                                                const ushort_t* __restrict__ vTg,
                                                const float* __restrict__ sp,
                                                const float* __restrict__ scale_p,
                                                float* __restrict__ po,
                                                float* __restrict__ pml) {
    __shared__ __align__(16) ushort_t p_s[16][72];  // 2.3 KB, wave-private
    const int bid = blockIdx.x;          // 0..4095
    const int half = bid & 1;
    const int h = (bid >> 1) & 3;
    const int qt = bid >> 3;             // 0..511
    const int lane = threadIdx.x;
    const int l15 = lane & 15, quad = lane >> 4;
    const int qrow = qt * 16 + l15;
    const float scale2 = scale_p[0] * 1.4426950408889634f;  // log2e folded
    const int k0 = half * (NROWS / 2);

    const bf16x8 bq = *(const bf16x8*)(qkb + (size_t)qrow * 256 + h * 32 + quad * 8);

    // pipeline registers: K/V 1 tile ahead, bias 2 tiles ahead
    bf16x8 af[4], vf[2][2];
    float4 pb[2][4];
#pragma unroll
    for (int c = 0; c < 4; ++c)
        af[c] = *(const bf16x8*)(qkb + (size_t)(k0 + c * 16 + l15) * 256 + 128 + h * 32 + quad * 8);
#pragma unroll
    for (int dt = 0; dt < 2; ++dt)
#pragma unroll
        for (int kc = 0; kc < 2; ++kc)
            vf[dt][kc] = *(const bf16x8*)(vTg + (size_t)(h * 32 + dt * 16 + l15) * NROWS + k0 + kc * 32 + quad * 8);
#pragma unroll
    for (int pp = 0; pp < 2; ++pp)
#pragma unroll
        for (int c = 0; c < 4; ++c)
            pb[pp][c] = *(const float4*)(sp + (size_t)qrow * NROWS + k0 + pp * 64 + c * 16 + quad * 4);

    f32x4 oacc[2] = {};
    float m = -1e30f, l = 0.f;

    for (int it = 0; it < 64; ++it) {
        const int cur = it & 1;
        const int kt = k0 + it * 64;
        // C-init from 2-deep prefetched bias
        f32x4 sacc[4];
#pragma unroll
        for (int c = 0; c < 4; ++c) {
            sacc[c][0] = bias_of(pb[cur][c].x, scale2);
            sacc[c][1] = bias_of(pb[cur][c].y, scale2);
            sacc[c][2] = bias_of(pb[cur][c].z, scale2);
            sacc[c][3] = bias_of(pb[cur][c].w, scale2);
        }
        // QK^T (scores in log2 domain)
#pragma unroll
        for (int c = 0; c < 4; ++c)
            sacc[c] = __builtin_amdgcn_mfma_f32_16x16x32_bf16(af[c], bq, sacc[c], 0, 0, 0);
        // prefetch next K fragments (issue order K -> V -> bias keeps vmcnt waits cheap)
        if (it < 63) {
            int kn = kt + 64;
#pragma unroll
            for (int c = 0; c < 4; ++c)
                af[c] = *(const bf16x8*)(qkb + (size_t)(kn + c * 16 + l15) * 256 + 128 + h * 32 + quad * 8);
        }
        // online softmax (base-2; state in-lane, reduce across quads)
        float tmax = -1e30f;
#pragma unroll
        for (int c = 0; c < 4; ++c)
#pragma unroll
            for (int r = 0; r < 4; ++r) tmax = fmaxf(tmax, sacc[c][r]);
        tmax = fmaxf(tmax, __shfl_xor(tmax, 16, 64));
        tmax = fmaxf(tmax, __shfl_xor(tmax, 32, 64));
        float mnew = fmaxf(m, tmax);
        float alpha = exp2_fast(m - mnew);
        float lsum = 0.f;
#pragma unroll
        for (int c = 0; c < 4; ++c)
#pragma unroll
            for (int r = 0; r < 4; ++r) {
                float p = exp2_fast(sacc[c][r] - mnew);
                sacc[c][r] = p;
                lsum += p;
            }
        lsum += __shfl_xor(lsum, 16, 64);
        lsum += __shfl_xor(lsum, 32, 64);
        l = l * alpha + lsum;
        m = mnew;
        oacc[0][0] *= alpha; oacc[0][1] *= alpha; oacc[0][2] *= alpha; oacc[0][3] *= alpha;
        oacc[1][0] *= alpha; oacc[1][1] *= alpha; oacc[1][2] *= alpha; oacc[1][3] *= alpha;
        // write P: truncating bf16 pack via v_perm (P in [0,1], trunc err < 0.4%)
#pragma unroll
        for (int c = 0; c < 4; ++c) {
            unsigned b0 = __float_as_uint(sacc[c][0]);
            unsigned b1 = __float_as_uint(sacc[c][1]);
            unsigned b2 = __float_as_uint(sacc[c][2]);
            unsigned b3 = __float_as_uint(sacc[c][3]);
            uint2 pw;
            pw.x = __builtin_amdgcn_perm(b1, b0, 0x07060302);
            pw.y = __builtin_amdgcn_perm(b3, b2, 0x07060302);
            *(uint2*)&p_s[l15][c * 16 + quad * 4] = pw;
        }
        asm volatile("s_waitcnt lgkmcnt(0)" ::: "memory");  // same-wave P RAW
        bf16x8 pf0 = *(const bf16x8*)&p_s[l15][quad * 8];
        bf16x8 pf1 = *(const bf16x8*)&p_s[l15][32 + quad * 8];
        // PV: O^T += V^T . P^T
        oacc[0] = __builtin_amdgcn_mfma_f32_16x16x32_bf16(vf[0][0], pf0, oacc[0], 0, 0, 0);
        oacc[0] = __builtin_amdgcn_mfma_f32_16x16x32_bf16(vf[0][1], pf1, oacc[0], 0, 0, 0);
        oacc[1] = __builtin_amdgcn_mfma_f32_16x16x32_bf16(vf[1][0], pf0, oacc[1], 0, 0, 0);
        oacc[1] = __builtin_amdgcn_mfma_f32_16x16x32_bf16(vf[1][1], pf1, oacc[1], 0, 0, 0);
        if (it < 63) {
            int kn = kt + 64;
#pragma unroll
            for (int dt = 0; dt < 2; ++dt)
#pragma unroll
                for (int kc = 0; kc < 2; ++kc)
                    vf[dt][kc] = *(const bf16x8*)(vTg + (size_t)(h * 32 + dt * 16 + l15) * NROWS + kn + kc * 32 + quad * 8);
            if (it < 62) {
#pragma unroll
                for (int c = 0; c < 4; ++c)
                    pb[cur][c] = *(const float4*)(sp + (size_t)qrow * NROWS + kt + 128 + c * 16 + quad * 4);
            }
        }
    }
    // write partials (unnormalized O^T, m, l)
    size_t base = ((size_t)qrow * 4 + h) * 2 + half;
    if (quad == 0) {
        pml[base * 2 + 0] = m;
        pml[base * 2 + 1] = l;
    }
#pragma unroll
    for (int dt = 0; dt < 2; ++dt)
#pragma unroll
        for (int r = 0; r < 4; ++r)
            po[base * 32 + dt * 16 + quad * 4 + r] = oacc[dt][r];
}

// ---------- K3: merge the two key-halves ----------
__global__ __launch_bounds__(256) void k_merge(const float* __restrict__ po,
                                               const float* __restrict__ pml,
                                               ushort_t* __restrict__ obuf) {
    int gid = blockIdx.x * 256 + threadIdx.x;  // 131072 = 8192 q * 4 h * 4 dchunks
    int qh = gid >> 2;
    int dp = (gid & 3) * 8;
    float m0 = pml[(size_t)qh * 4 + 0], l0 = pml[(size_t)qh * 4 + 1];
    float m1 = pml[(size_t)qh * 4 + 2], l1 = pml[(size_t)qh * 4 + 3];
    float mm = fmaxf(m0, m1);
    float a0 = exp2_fast(m0 - mm), a1 = exp2_fast(m1 - mm);
    float linv = 1.f / (l0 * a0 + l1 * a1);
    a0 *= linv; a1 *= linv;
    const float* p0 = po + ((size_t)qh * 2 + 0) * 32 + dp;
    const float* p1 = po + ((size_t)qh * 2 + 1) * 32 + dp;
    float4 x0 = *(const float4*)p0, y0 = *(const float4*)(p0 + 4);
    float4 x1 = *(const float4*)p1, y1 = *(const float4*)(p1 + 4);
    int q = qh >> 2, h = qh & 3;
    ushort_t* dst = obuf + (size_t)q * HID + h * 32 + dp;
    short4v s0 = {f2bf(x0.x * a0 + x1.x * a1), f2bf(x0.y * a0 + x1.y * a1),
                  f2bf(x0.z * a0 + x1.z * a1), f2bf(x0.w * a0 + x1.w * a1)};
    short4v s1 = {f2bf(y0.x * a0 + y1.x * a1), f2bf(y0.y * a0 + y1.y * a1),
                  f2bf(y0.z * a0 + y1.z * a1), f2bf(y0.w * a0 + y1.w * a1)};
    *(short4v*)dst = s0;
    *(short4v*)(dst + 4) = s1;
}

// ---------- K4: epilogue: out_proj -> relu+residual -> W_out -> log_softmax ----------
__global__ __launch_bounds__(256) void k_epi(const ushort_t* __restrict__ hbf,
                                             const ushort_t* __restrict__ obuf,
                                             const ushort_t* __restrict__ wob,
                                             const float* __restrict__ bo,
                                             const ushort_t* __restrict__ woutb,
                                             const float* __restrict__ bout,
                                             float* __restrict__ out) {
    __shared__ __align__(16) ushort_t hr_s[32][136];
    const int w = threadIdx.x >> 6, lane = threadIdx.x & 63;
    const int l15 = lane & 15, quad = lane >> 4;
    const int r0 = blockIdx.x * 32;

    // phase A: o2 = obuf @ Wo^T + bo -> relu -> + h -> hr_s (bf16)
    {
        const int n0 = w * 32;
        bf16x8 af[2][4], bfr[2][4];
#pragma unroll
        for (int mt = 0; mt < 2; ++mt)
#pragma unroll
            for (int kf = 0; kf < 4; ++kf)
                af[mt][kf] = *(const bf16x8*)(obuf + (size_t)(r0 + mt * 16 + l15) * 128 + kf * 32 + quad * 8);
#pragma unroll
        for (int nt = 0; nt < 2; ++nt)
#pragma unroll
            for (int kf = 0; kf < 4; ++kf)
                bfr[nt][kf] = *(const bf16x8*)(wob + (size_t)(n0 + nt * 16 + l15) * 128 + kf * 32 + quad * 8);
#pragma unroll
        for (int mt = 0; mt < 2; ++mt)
#pragma unroll
            for (int nt = 0; nt < 2; ++nt) {
                float bias = bo[n0 + nt * 16 + l15];
                f32x4 c = {bias, bias, bias, bias};
#pragma unroll
                for (int kf = 0; kf < 4; ++kf)
                    c = __builtin_amdgcn_mfma_f32_16x16x32_bf16(af[mt][kf], bfr[nt][kf], c, 0, 0, 0);
                int col = n0 + nt * 16 + l15;
#pragma unroll
                for (int r = 0; r < 4; ++r) {
                    int row = mt * 16 + quad * 4 + r;
                    float val = fmaxf(c[r], 0.f) + bf2f(hbf[(size_t)(r0 + row) * 128 + col]);
                    hr_s[row][col] = (ushort_t)f2bf(val);
                }
            }
    }
    __syncthreads();
    // phase B: logits^T = Wout . hr^T ; in-lane log_softmax per row
    if (w < 2) {
        const int n0 = w * 16;
        f32x4 c[3];
#pragma unroll
        for (int mt = 0; mt < 3; ++mt)
#pragma unroll
            for (int r = 0; r < 4; ++r) {
                int oc = mt * 16 + quad * 4 + r;
                c[mt][r] = (oc < OUTC) ? bout[oc] : 0.f;
            }
#pragma unroll
        for (int kf = 0; kf < 4; ++kf) {
            bf16x8 bfrag = *(const bf16x8*)&hr_s[n0 + l15][kf * 32 + quad * 8];
#pragma unroll
            for (int mt = 0; mt < 3; ++mt) {
                int oc = mt * 16 + l15;
                int occ = oc < OUTC ? oc : (OUTC - 1);
                bf16x8 afr = *(const bf16x8*)(woutb + (size_t)occ * 128 + kf * 32 + quad * 8);
                if (oc >= OUTC) {
#pragma unroll
                    for (int j = 0; j < 8; ++j) afr[j] = 0;
                }
                c[mt] = __builtin_amdgcn_mfma_f32_16x16x32_bf16(afr, bfrag, c[mt], 0, 0, 0);
            }
        }
        float mx = -1e30f;
#pragma unroll
        for (int mt = 0; mt < 3; ++mt)
#pragma unroll
            for (int r = 0; r < 4; ++r) {
                int oc = mt * 16 + quad * 4 + r;
                if (oc >= OUTC) c[mt][r] = -1e30f;
                mx = fmaxf(mx, c[mt][r]);
            }
        mx = fmaxf(mx, __shfl_xor(mx, 16, 64));
        mx = fmaxf(mx, __shfl_xor(mx, 32, 64));
        float ssum = 0.f;
#pragma unroll
        for (int mt = 0; mt < 3; ++mt)
#pragma unroll
            for (int r = 0; r < 4; ++r) ssum += __expf(c[mt][r] - mx);
        ssum += __shfl_xor(ssum, 16, 64);
        ssum += __shfl_xor(ssum, 32, 64);
        float lse = __logf(ssum) + mx;
        int row = r0 + n0 + l15;
#pragma unroll
        for (int mt = 0; mt < 2; ++mt) {
            float4 st = make_float4(c[mt][0] - lse, c[mt][1] - lse, c[mt][2] - lse, c[mt][3] - lse);
            *(float4*)(out + (size_t)row * OUTC + mt * 16 + quad * 4) = st;
        }
        if (quad < 2) {
            float4 st = make_float4(c[2][0] - lse, c[2][1] - lse, c[2][2] - lse, c[2][3] - lse);
            *(float4*)(out + (size_t)row * OUTC + 32 + quad * 4) = st;
        }
    }
}

extern "C" void kernel_launch(void* const* d_in, const int* in_sizes, int n_in,
                              void* d_out, int out_size, void* d_ws, size_t ws_size,
                              hipStream_t stream) {
    const float* x          = (const float*)d_in[0];
    // d_in[1] = pos_enc (unused in forward, faithful to reference)
    const float* sp         = (const float*)d_in[2];
    const float* W_in       = (const float*)d_in[3];
    const float* b_in       = (const float*)d_in[4];
    const float* in_proj_w  = (const float*)d_in[5];
    const float* in_proj_b  = (const float*)d_in[6];
    const float* out_proj_w = (const float*)d_in[7];
    const float* out_proj_b = (const float*)d_in[8];
    const float* W_out      = (const float*)d_in[9];
    const float* b_out      = (const float*)d_in[10];
    const float* scale      = (const float*)d_in[11];

    // f32 workspace first (alignment), then bf16 buffers
    float*    po    = (float*)d_ws;                        // 8192*4*2*32 f32 = 8 MiB
    float*    pml   = po + (size_t)NROWS * 4 * 2 * 32;     // 8192*4*2*2 f32 = 0.5 MiB
    ushort_t* hbf   = (ushort_t*)(pml + (size_t)NROWS * 4 * 4);
    ushort_t* qkb   = hbf + (size_t)NROWS * 128;           // [token][q|k]
    ushort_t* vTg   = qkb + (size_t)NROWS * 256;           // [d][token]
    ushort_t* obuf  = vTg + (size_t)128 * NROWS;
    ushort_t* xb    = obuf + (size_t)NROWS * 128;
    ushort_t* wib   = xb + (size_t)NROWS * 128;
    ushort_t* wpb   = wib + 128 * 128;
    ushort_t* wob   = wpb + 384 * 128;
    ushort_t* woutb = wob + 128 * 128;
    float*    out   = (float*)d_out;

    hipLaunchKernelGGL(k_prep, dim3(555), dim3(256), 0, stream,
                       x, W_in, in_proj_w, out_proj_w, W_out, xb, wib, wpb, wob, woutb);
    hipLaunchKernelGGL(k_qkv_fused, dim3(NROWS / 32), dim3(256), 0, stream,
                       xb, wib, b_in, wpb, in_proj_b, hbf, qkb, vTg);
    hipLaunchKernelGGL(k_attn, dim3((NROWS / 16) * 4 * 2), dim3(64), 0, stream,
                       qkb, vTg, sp, scale, po, pml);
    hipLaunchKernelGGL(k_merge, dim3(NROWS * 4 * 4 / 256), dim3(256), 0, stream,
                       po, pml, obuf);
    hipLaunchKernelGGL(k_epi, dim3(NROWS / 32), dim3(256), 0, stream,
                       hbf, obuf, wob, out_proj_b, woutb, b_out, out);
}

// Round 7
// 588.088 us; speedup vs baseline: 1.5818x; 1.5818x over previous
//
#include <hip/hip_runtime.h>
#include <hip/hip_bf16.h>
#include <hip/hip_runtime_api.h>

// Problem constants
#define NROWS 8192
#define HID 128
#define OUTC 40

typedef unsigned short ushort_t;
typedef __attribute__((ext_vector_type(8))) short bf16x8;
typedef __attribute__((ext_vector_type(4))) short short4v;
typedef __attribute__((ext_vector_type(4))) float f32x4;

// f32 -> bf16 RNE
__device__ __forceinline__ short f2bf(float f) {
    unsigned int u = __float_as_uint(f);
    unsigned int r = (u + 0x7FFFu + ((u >> 16) & 1u)) >> 16;
    return (short)r;
}
__device__ __forceinline__ float bf2f(ushort_t b) {
    return __uint_as_float(((unsigned int)b) << 16);
}

__device__ __forceinline__ float exp2_fast(float x) {
#if __has_builtin(__builtin_amdgcn_exp2f)
    return __builtin_amdgcn_exp2f(x);
#else
    return exp2f(x);
#endif
}

// bias (log2 domain): r = scale2/d ; d==0 -> inf -> 0 (sp is finite randint 0..10)
__device__ __forceinline__ float bias_of(float f, float scale2) {
    float r = scale2 * __builtin_amdgcn_rcpf(f);
    bool bad = (__float_as_uint(r) & 0x7F800000u) == 0x7F800000u;
    return bad ? 0.f : r;
}

// ---------- K0: one-time f32 -> bf16 conversion of x and all weights ----------
__global__ __launch_bounds__(256) void k_prep(const float* __restrict__ x,
                                              const float* __restrict__ Wi,
                                              const float* __restrict__ Wp,
                                              const float* __restrict__ Wo,
                                              const float* __restrict__ Wout,
                                              ushort_t* __restrict__ xb,
                                              ushort_t* __restrict__ wib,
                                              ushort_t* __restrict__ wpb,
                                              ushort_t* __restrict__ wob,
                                              ushort_t* __restrict__ woutb) {
    int rb = blockIdx.x;
    const float* src; ushort_t* dst; int n, base;
    if (rb < 512)      { src = x;    dst = xb;    n = NROWS * 128; base = rb; }
    else if (rb < 520) { src = Wi;   dst = wib;   n = 128 * 128;   base = rb - 512; }
    else if (rb < 544) { src = Wp;   dst = wpb;   n = 384 * 128;   base = rb - 520; }
    else if (rb < 552) { src = Wo;   dst = wob;   n = 128 * 128;   base = rb - 544; }
    else               { src = Wout; dst = woutb; n = OUTC * 128;  base = rb - 552; }
    int i0 = base * 2048 + threadIdx.x * 8;
    if (i0 < n) {
        float4 a = *(const float4*)(src + i0);
        float4 b = *(const float4*)(src + i0 + 4);
        short4v s0 = {f2bf(a.x), f2bf(a.y), f2bf(a.z), f2bf(a.w)};
        short4v s1 = {f2bf(b.x), f2bf(b.y), f2bf(b.z), f2bf(b.w)};
        *(short4v*)(dst + i0) = s0;
        *(short4v*)(dst + i0 + 4) = s1;
    }
}

// ---------- K1: fused h = x@Wi^T+bi -> qkv = h@Wp^T+bp (16 rows/block) ----------
// Emits: hbf (residual), qkb[token][256] (q|k, q pre-scaled by log2e/sqrt(hd)), vTg[d][token]
__global__ __launch_bounds__(256) void k_qkv_fused(const ushort_t* __restrict__ xb,
                                                   const ushort_t* __restrict__ wib,
                                                   const float* __restrict__ bi,
                                                   const ushort_t* __restrict__ wpb,
                                                   const float* __restrict__ bp,
                                                   ushort_t* __restrict__ hbf,
                                                   ushort_t* __restrict__ qkb,
                                                   ushort_t* __restrict__ vTg) {
    __shared__ __align__(16) ushort_t h_s[16][136];
    const int w = threadIdx.x >> 6, lane = threadIdx.x & 63;
    const int l15 = lane & 15, quad = lane >> 4;
    const int r0 = blockIdx.x * 16;

    // phase 1: 16 rows, wave w owns output cols w*32..w*32+31
    {
        const int n0 = w * 32;
        bf16x8 af[4], bfr[2][4];
#pragma unroll
        for (int kf = 0; kf < 4; ++kf)
            af[kf] = *(const bf16x8*)(xb + (size_t)(r0 + l15) * 128 + kf * 32 + quad * 8);
#pragma unroll
        for (int nt = 0; nt < 2; ++nt)
#pragma unroll
            for (int kf = 0; kf < 4; ++kf)
                bfr[nt][kf] = *(const bf16x8*)(wib + (size_t)(n0 + nt * 16 + l15) * 128 + kf * 32 + quad * 8);
#pragma unroll
        for (int nt = 0; nt < 2; ++nt) {
            float bias = bi[n0 + nt * 16 + l15];
            f32x4 c = {bias, bias, bias, bias};
#pragma unroll
            for (int kf = 0; kf < 4; ++kf)
                c = __builtin_amdgcn_mfma_f32_16x16x32_bf16(af[kf], bfr[nt][kf], c, 0, 0, 0);
            int col = n0 + nt * 16 + l15;
#pragma unroll
            for (int r = 0; r < 4; ++r) {
                int row = quad * 4 + r;
                short hv = f2bf(c[r]);
                h_s[row][col] = (ushort_t)hv;
                hbf[(size_t)(r0 + row) * 128 + col] = (ushort_t)hv;
            }
        }
    }
    __syncthreads();
    // phase 2: qkv (wave w owns output cols w*96..w*96+95)
    bf16x8 af2[4];
#pragma unroll
    for (int kf = 0; kf < 4; ++kf)
        af2[kf] = *(const bf16x8*)&h_s[l15][kf * 32 + quad * 8];
    const float QS = 0.25503482459918643f;  // log2e / sqrt(32)
#pragma unroll
    for (int nt = 0; nt < 6; ++nt) {
        const int n0 = w * 96 + nt * 16;
        bf16x8 bfr[4];
#pragma unroll
        for (int kf = 0; kf < 4; ++kf)
            bfr[kf] = *(const bf16x8*)(wpb + (size_t)(n0 + l15) * 128 + kf * 32 + quad * 8);
        float bias = bp[n0 + l15];
        float sc = (n0 < 128) ? QS : 1.0f;
        f32x4 c = {bias, bias, bias, bias};
#pragma unroll
        for (int kf = 0; kf < 4; ++kf)
            c = __builtin_amdgcn_mfma_f32_16x16x32_bf16(af2[kf], bfr[kf], c, 0, 0, 0);
        if (n0 < 256) {  // q or k -> token-major
#pragma unroll
            for (int r = 0; r < 4; ++r)
                qkb[(size_t)(r0 + quad * 4 + r) * 256 + n0 + l15] = (ushort_t)f2bf(c[r] * sc);
        } else {  // v -> transposed [d][token], packed b64
            int vd = n0 + l15 - 256;
            short4v pk = {f2bf(c[0]), f2bf(c[1]), f2bf(c[2]), f2bf(c[3])};
            *(short4v*)&vTg[(size_t)vd * NROWS + r0 + quad * 4] = pk;
        }
    }
}

// ---------- K2: flash attention partials ----------
// Block = 4 head-waves x (qt, key-half). K/V: direct-global per-wave MFMA fragments
// (heads partition channels -> no redundancy). Bias: cooperatively staged f32 LDS,
// double-buffered, one barrier/iter -> each sp element read ONCE device-wide.
// S^T = K.Q^T (C: col=l15=q, row=quad*4+r=key); O^T = V^T.P^T. Log2-domain softmax.
__global__ __launch_bounds__(256, 4) void k_attn(const ushort_t* __restrict__ qkb,
                                                 const ushort_t* __restrict__ vTg,
                                                 const float* __restrict__ sp,
                                                 const float* __restrict__ scale_p,
                                                 float* __restrict__ po,
                                                 float* __restrict__ pml) {
    __shared__ __align__(16) float bias_s[2][16][68];   // 8.7 KB
    __shared__ __align__(16) ushort_t p_s[4][16][72];   // 9.2 KB

    const int t = threadIdx.x;
    const int h = t >> 6;  // wave = head
    const int lane = t & 63, l15 = lane & 15, quad = lane >> 4;
    const int qt = blockIdx.x & 511;
    const int half = blockIdx.x >> 9;
    const int q0 = qt * 16;
    const int k0 = half * (NROWS / 2);
    const float scale2 = scale_p[0] * 1.4426950408889634f;  // log2e folded

    // bias staging role: thread t loads sp[q0 + (t>>4)][kt + (t&15)*4]
    const int brow = t >> 4, bcol = (t & 15) * 4;
    const float* sp_base = sp + (size_t)(q0 + brow) * NROWS + k0 + bcol;

    // loop-invariant Q^T B-fragment (pre-scaled)
    const bf16x8 bq = *(const bf16x8*)(qkb + (size_t)(q0 + l15) * 256 + h * 32 + quad * 8);

    // K/V fragment pipeline registers (1 tile ahead)
    bf16x8 af[4], vf[2][2];
#pragma unroll
    for (int c = 0; c < 4; ++c)
        af[c] = *(const bf16x8*)(qkb + (size_t)(k0 + c * 16 + l15) * 256 + 128 + h * 32 + quad * 8);
#pragma unroll
    for (int dt = 0; dt < 2; ++dt)
#pragma unroll
        for (int kc = 0; kc < 2; ++kc)
            vf[dt][kc] = *(const bf16x8*)(vTg + (size_t)(h * 32 + dt * 16 + l15) * NROWS + k0 + kc * 32 + quad * 8);

    // bias prologue: stage tile 0, load tile 1 into regs
    {
        float4 b0 = *(const float4*)sp_base;
        f32x4 cv = {bias_of(b0.x, scale2), bias_of(b0.y, scale2),
                    bias_of(b0.z, scale2), bias_of(b0.w, scale2)};
        *(f32x4*)&bias_s[0][brow][bcol] = cv;
    }
    float4 breg = *(const float4*)(sp_base + 64);
    __syncthreads();

    f32x4 oacc[2] = {};
    float m = -1e30f, l = 0.f;

    for (int it = 0; it < 64; ++it) {
        const int cur = it & 1;
        // C-init from staged bias
        f32x4 sacc[4];
#pragma unroll
        for (int c = 0; c < 4; ++c)
            sacc[c] = *(const f32x4*)&bias_s[cur][l15][c * 16 + quad * 4];
        // QK^T (scores in log2 domain)
#pragma unroll
        for (int c = 0; c < 4; ++c)
            sacc[c] = __builtin_amdgcn_mfma_f32_16x16x32_bf16(af[c], bq, sacc[c], 0, 0, 0);
        // prefetch next K fragments
        if (it < 63) {
            int kn = k0 + (it + 1) * 64;
#pragma unroll
            for (int c = 0; c < 4; ++c)
                af[c] = *(const bf16x8*)(qkb + (size_t)(kn + c * 16 + l15) * 256 + 128 + h * 32 + quad * 8);
        }
        // online softmax (base-2; state in-lane, reduce across quads)
        float tmax = -1e30f;
#pragma unroll
        for (int c = 0; c < 4; ++c)
#pragma unroll
            for (int r = 0; r < 4; ++r) tmax = fmaxf(tmax, sacc[c][r]);
        tmax = fmaxf(tmax, __shfl_xor(tmax, 16, 64));
        tmax = fmaxf(tmax, __shfl_xor(tmax, 32, 64));
        float mnew = fmaxf(m, tmax);
        float alpha = exp2_fast(m - mnew);
        float lsum = 0.f;
#pragma unroll
        for (int c = 0; c < 4; ++c)
#pragma unroll
            for (int r = 0; r < 4; ++r) {
                float p = exp2_fast(sacc[c][r] - mnew);
                sacc[c][r] = p;
                lsum += p;
            }
        lsum += __shfl_xor(lsum, 16, 64);
        lsum += __shfl_xor(lsum, 32, 64);
        l = l * alpha + lsum;
        m = mnew;
        oacc[0][0] *= alpha; oacc[0][1] *= alpha; oacc[0][2] *= alpha; oacc[0][3] *= alpha;
        oacc[1][0] *= alpha; oacc[1][1] *= alpha; oacc[1][2] *= alpha; oacc[1][3] *= alpha;
        // write P: truncating bf16 pack via v_perm (P in (0,1], trunc err < 0.4%)
#pragma unroll
        for (int c = 0; c < 4; ++c) {
            unsigned b0 = __float_as_uint(sacc[c][0]);
            unsigned b1 = __float_as_uint(sacc[c][1]);
            unsigned b2 = __float_as_uint(sacc[c][2]);
            unsigned b3 = __float_as_uint(sacc[c][3]);
            uint2 pw;
            pw.x = __builtin_amdgcn_perm(b1, b0, 0x07060302);
            pw.y = __builtin_amdgcn_perm(b3, b2, 0x07060302);
            *(uint2*)&p_s[h][l15][c * 16 + quad * 4] = pw;
        }
        asm volatile("s_waitcnt lgkmcnt(0)" ::: "memory");  // same-wave P RAW
        bf16x8 pf0 = *(const bf16x8*)&p_s[h][l15][quad * 8];
        bf16x8 pf1 = *(const bf16x8*)&p_s[h][l15][32 + quad * 8];
        // PV: O^T += V^T . P^T
        oacc[0] = __builtin_amdgcn_mfma_f32_16x16x32_bf16(vf[0][0], pf0, oacc[0], 0, 0, 0);
        oacc[0] = __builtin_amdgcn_mfma_f32_16x16x32_bf16(vf[0][1], pf1, oacc[0], 0, 0, 0);
        oacc[1] = __builtin_amdgcn_mfma_f32_16x16x32_bf16(vf[1][0], pf0, oacc[1], 0, 0, 0);
        oacc[1] = __builtin_amdgcn_mfma_f32_16x16x32_bf16(vf[1][1], pf1, oacc[1], 0, 0, 0);
        // prefetch next V fragments
        if (it < 63) {
            int kn = k0 + (it + 1) * 64;
#pragma unroll
            for (int dt = 0; dt < 2; ++dt)
#pragma unroll
                for (int kc = 0; kc < 2; ++kc)
                    vf[dt][kc] = *(const bf16x8*)(vTg + (size_t)(h * 32 + dt * 16 + l15) * NROWS + kn + kc * 32 + quad * 8);
        }
        // stage next bias tile from regs; fetch tile it+2
        if (it < 63) {
            f32x4 cv = {bias_of(breg.x, scale2), bias_of(breg.y, scale2),
                        bias_of(breg.z, scale2), bias_of(breg.w, scale2)};
            *(f32x4*)&bias_s[1 - cur][brow][bcol] = cv;
            if (it < 62) breg = *(const float4*)(sp_base + (it + 2) * 64);
        }
        __syncthreads();
    }
    // write partials (unnormalized O^T, m, l) in log2 domain
    size_t base = ((size_t)(q0 + l15) * 4 + h) * 2 + half;
    if (quad == 0) {
        pml[base * 2 + 0] = m;
        pml[base * 2 + 1] = l;
    }
#pragma unroll
    for (int dt = 0; dt < 2; ++dt)
#pragma unroll
        for (int r = 0; r < 4; ++r)
            po[base * 32 + dt * 16 + quad * 4 + r] = oacc[dt][r];
}

// ---------- K3: epilogue (merge + out_proj -> relu+residual -> W_out -> log_softmax) ----------
// 16 rows/block, grid 512. Phase A builds A-fragments directly from po/pml (split-K merge in-register).
__global__ __launch_bounds__(256) void k_epi(const ushort_t* __restrict__ hbf,
                                             const float* __restrict__ po,
                                             const float* __restrict__ pml,
                                             const ushort_t* __restrict__ wob,
                                             const float* __restrict__ bo,
                                             const ushort_t* __restrict__ woutb,
                                             const float* __restrict__ bout,
                                             float* __restrict__ out) {
    __shared__ __align__(16) ushort_t hr_s[16][136];
    const int w = threadIdx.x >> 6, lane = threadIdx.x & 63;
    const int l15 = lane & 15, quad = lane >> 4;
    const int r0 = blockIdx.x * 16;

    // phase A: merged attention output as A-fragments; o2 = o @ Wo^T + bo -> relu -> +h
    {
        const int n0 = w * 32;
        bf16x8 af[4];
#pragma unroll
        for (int kf = 0; kf < 4; ++kf) {  // kf = head
            int row = r0 + l15;
            float4 ml = *(const float4*)(pml + ((size_t)row * 4 + kf) * 4);  // m0,l0,m1,l1
            float mm = fmaxf(ml.x, ml.z);
            float a0 = exp2_fast(ml.x - mm), a1 = exp2_fast(ml.z - mm);
            float linv = 1.f / (ml.y * a0 + ml.w * a1);
            a0 *= linv; a1 *= linv;
            const float* p0 = po + (((size_t)row * 4 + kf) * 2 + 0) * 32 + quad * 8;
            const float* p1 = p0 + 32;
            float4 x0 = *(const float4*)p0, y0 = *(const float4*)(p0 + 4);
            float4 x1 = *(const float4*)p1, y1 = *(const float4*)(p1 + 4);
            bf16x8 a;
            a[0] = f2bf(x0.x * a0 + x1.x * a1); a[1] = f2bf(x0.y * a0 + x1.y * a1);
            a[2] = f2bf(x0.z * a0 + x1.z * a1); a[3] = f2bf(x0.w * a0 + x1.w * a1);
            a[4] = f2bf(y0.x * a0 + y1.x * a1); a[5] = f2bf(y0.y * a0 + y1.y * a1);
            a[6] = f2bf(y0.z * a0 + y1.z * a1); a[7] = f2bf(y0.w * a0 + y1.w * a1);
            af[kf] = a;
        }
        bf16x8 bfr[2][4];
#pragma unroll
        for (int nt = 0; nt < 2; ++nt)
#pragma unroll
            for (int kf = 0; kf < 4; ++kf)
                bfr[nt][kf] = *(const bf16x8*)(wob + (size_t)(n0 + nt * 16 + l15) * 128 + kf * 32 + quad * 8);
#pragma unroll
        for (int nt = 0; nt < 2; ++nt) {
            float bias = bo[n0 + nt * 16 + l15];
            f32x4 c = {bias, bias, bias, bias};
#pragma unroll
            for (int kf = 0; kf < 4; ++kf)
                c = __builtin_amdgcn_mfma_f32_16x16x32_bf16(af[kf], bfr[nt][kf], c, 0, 0, 0);
            int col = n0 + nt * 16 + l15;
#pragma unroll
            for (int r = 0; r < 4; ++r) {
                int row = quad * 4 + r;
                float val = fmaxf(c[r], 0.f) + bf2f(hbf[(size_t)(r0 + row) * 128 + col]);
                hr_s[row][col] = (ushort_t)f2bf(val);
            }
        }
    }
    __syncthreads();
    // phase B (wave 0): logits^T = Wout . hr^T ; in-lane log_softmax per row
    if (w == 0) {
        f32x4 c[3];
#pragma unroll
        for (int mt = 0; mt < 3; ++mt)
#pragma unroll
            for (int r = 0; r < 4; ++r) {
                int oc = mt * 16 + quad * 4 + r;
                c[mt][r] = (oc < OUTC) ? bout[oc] : 0.f;
            }
#pragma unroll
        for (int kf = 0; kf < 4; ++kf) {
            bf16x8 bfrag = *(const bf16x8*)&hr_s[l15][kf * 32 + quad * 8];
#pragma unroll
            for (int mt = 0; mt < 3; ++mt) {
                int oc = mt * 16 + l15;
                int occ = oc < OUTC ? oc : (OUTC - 1);
                bf16x8 afr = *(const bf16x8*)(woutb + (size_t)occ * 128 + kf * 32 + quad * 8);
                if (oc >= OUTC) {
#pragma unroll
                    for (int j = 0; j < 8; ++j) afr[j] = 0;
                }
                c[mt] = __builtin_amdgcn_mfma_f32_16x16x32_bf16(afr, bfrag, c[mt], 0, 0, 0);
            }
        }
        float mx = -1e30f;
#pragma unroll
        for (int mt = 0; mt < 3; ++mt)
#pragma unroll
            for (int r = 0; r < 4; ++r) {
                int oc = mt * 16 + quad * 4 + r;
                if (oc >= OUTC) c[mt][r] = -1e30f;
                mx = fmaxf(mx, c[mt][r]);
            }
        mx = fmaxf(mx, __shfl_xor(mx, 16, 64));
        mx = fmaxf(mx, __shfl_xor(mx, 32, 64));
        float ssum = 0.f;
#pragma unroll
        for (int mt = 0; mt < 3; ++mt)
#pragma unroll
            for (int r = 0; r < 4; ++r) ssum += __expf(c[mt][r] - mx);
        ssum += __shfl_xor(ssum, 16, 64);
        ssum += __shfl_xor(ssum, 32, 64);
        float lse = __logf(ssum) + mx;
        int row = r0 + l15;
#pragma unroll
        for (int mt = 0; mt < 2; ++mt) {
            float4 st = make_float4(c[mt][0] - lse, c[mt][1] - lse, c[mt][2] - lse, c[mt][3] - lse);
            *(float4*)(out + (size_t)row * OUTC + mt * 16 + quad * 4) = st;
        }
        if (quad < 2) {
            float4 st = make_float4(c[2][0] - lse, c[2][1] - lse, c[2][2] - lse, c[2][3] - lse);
            *(float4*)(out + (size_t)row * OUTC + 32 + quad * 4) = st;
        }
    }
}

extern "C" void kernel_launch(void* const* d_in, const int* in_sizes, int n_in,
                              void* d_out, int out_size, void* d_ws, size_t ws_size,
                              hipStream_t stream) {
    const float* x          = (const float*)d_in[0];
    // d_in[1] = pos_enc (unused in forward, faithful to reference)
    const float* sp         = (const float*)d_in[2];
    const float* W_in       = (const float*)d_in[3];
    const float* b_in       = (const float*)d_in[4];
    const float* in_proj_w  = (const float*)d_in[5];
    const float* in_proj_b  = (const float*)d_in[6];
    const float* out_proj_w = (const float*)d_in[7];
    const float* out_proj_b = (const float*)d_in[8];
    const float* W_out      = (const float*)d_in[9];
    const float* b_out      = (const float*)d_in[10];
    const float* scale      = (const float*)d_in[11];

    float*    po    = (float*)d_ws;                        // 8192*4*2*32 f32 = 8 MiB
    float*    pml   = po + (size_t)NROWS * 4 * 2 * 32;     // 8192*4*4 f32 = 0.5 MiB
    ushort_t* hbf   = (ushort_t*)(pml + (size_t)NROWS * 4 * 4);
    ushort_t* qkb   = hbf + (size_t)NROWS * 128;           // [token][q|k]
    ushort_t* vTg   = qkb + (size_t)NROWS * 256;           // [d][token]
    ushort_t* xb    = vTg + (size_t)128 * NROWS;
    ushort_t* wib   = xb + (size_t)NROWS * 128;
    ushort_t* wpb   = wib + 128 * 128;
    ushort_t* wob   = wpb + 384 * 128;
    ushort_t* woutb = wob + 128 * 128;
    float*    out   = (float*)d_out;

    hipLaunchKernelGGL(k_prep, dim3(555), dim3(256), 0, stream,
                       x, W_in, in_proj_w, out_proj_w, W_out, xb, wib, wpb, wob, woutb);
    hipLaunchKernelGGL(k_qkv_fused, dim3(NROWS / 16), dim3(256), 0, stream,
                       xb, wib, b_in, wpb, in_proj_b, hbf, qkb, vTg);
    hipLaunchKernelGGL(k_attn, dim3((NROWS / 16) * 2), dim3(256), 0, stream,
                       qkb, vTg, sp, scale, po, pml);
    hipLaunchKernelGGL(k_epi, dim3(NROWS / 16), dim3(256), 0, stream,
                       hbf, po, pml, wob, out_proj_b, woutb, b_out, out);
}

// Round 8
// 536.096 us; speedup vs baseline: 1.7352x; 1.0970x over previous
//
#include <hip/hip_runtime.h>
#include <hip/hip_bf16.h>
#include <hip/hip_runtime_api.h>

// Problem constants
#define NROWS 8192
#define HID 128
#define OUTC 40

typedef unsigned short ushort_t;
typedef __attribute__((ext_vector_type(8))) short bf16x8;
typedef __attribute__((ext_vector_type(4))) short short4v;
typedef __attribute__((ext_vector_type(4))) float f32x4;

// f32 -> bf16 RNE
__device__ __forceinline__ short f2bf(float f) {
    unsigned int u = __float_as_uint(f);
    unsigned int r = (u + 0x7FFFu + ((u >> 16) & 1u)) >> 16;
    return (short)r;
}
__device__ __forceinline__ float bf2f(ushort_t b) {
    return __uint_as_float(((unsigned int)b) << 16);
}
__device__ __forceinline__ float exp2_fast(float x) {
#if __has_builtin(__builtin_amdgcn_exp2f)
    return __builtin_amdgcn_exp2f(x);
#else
    return exp2f(x);
#endif
}
// bias (log2 domain): r = scale2/d ; d==0 -> inf -> 0 (sp is finite randint 0..10)
__device__ __forceinline__ float bias_of(float f, float scale2) {
    float r = scale2 * __builtin_amdgcn_rcpf(f);
    bool bad = (__float_as_uint(r) & 0x7F800000u) == 0x7F800000u;
    return bad ? 0.f : r;
}

// Generic A-fragment tile layout over [rows][128 cols]:
//   frag[rt=row/16][kf=col/32][quad=(col%32)/8][l15=row%16][j=col%8]
// -> a wave's load for (rt,kf): base + ((rt*4+kf)*4+quad)*128 + l15*8 : 1KB contiguous.

// ---------- K0: one-time f32 -> frag-ordered bf16 (x + all weights) ----------
__global__ __launch_bounds__(256) void k_prep(const float* __restrict__ x,
                                              const float* __restrict__ Wi,
                                              const float* __restrict__ Wp,
                                              const float* __restrict__ Wo,
                                              const float* __restrict__ Wout,
                                              ushort_t* __restrict__ xfr,
                                              ushort_t* __restrict__ wifr,
                                              ushort_t* __restrict__ wpfr,
                                              ushort_t* __restrict__ wofr,
                                              ushort_t* __restrict__ woutfr) {
    int rb = blockIdx.x;
    const float* src; ushort_t* dst; int rt; int nrows;
    if (rb < 512)      { src = x;    dst = xfr;    rt = rb;       nrows = 1 << 30; }
    else if (rb < 520) { src = Wi;   dst = wifr;   rt = rb - 512; nrows = 1 << 30; }
    else if (rb < 544) { src = Wp;   dst = wpfr;   rt = rb - 520; nrows = 1 << 30; }
    else if (rb < 552) { src = Wo;   dst = wofr;   rt = rb - 544; nrows = 1 << 30; }
    else               { src = Wout; dst = woutfr; rt = rb - 552; nrows = OUTC; }  // pad to 48 rows
    int t = threadIdx.x;
    int r = t >> 4, c8 = t & 15;
    int row = rt * 16 + r;
    float4 a = {0.f, 0.f, 0.f, 0.f}, b = {0.f, 0.f, 0.f, 0.f};
    if (row < nrows) {
        a = *(const float4*)(src + (size_t)row * 128 + c8 * 8);
        b = *(const float4*)(src + (size_t)row * 128 + c8 * 8 + 4);
    }
    short4v s0 = {f2bf(a.x), f2bf(a.y), f2bf(a.z), f2bf(a.w)};
    short4v s1 = {f2bf(b.x), f2bf(b.y), f2bf(b.z), f2bf(b.w)};
    ushort_t* d = dst + ((((size_t)rt * 4 + (c8 >> 2)) * 4 + (c8 & 3)) * 16 + r) * 8;
    *(short4v*)d = s0;
    *(short4v*)(d + 4) = s1;
}

// ---------- K1: fused h = x@Wi^T+bi -> qkv = h@Wp^T+bp (frag-ordered in/out) ----------
// Emits hbf (token-major residual), qfr/kfr (frag-ordered, q pre-scaled log2e/sqrt(hd)),
// vfr (B-operand frag order: [kb=key/32][h][dt][qk=(key%32)/8][l15=d%16][j=key%8]).
__global__ __launch_bounds__(256) void k_qkv_fused(const ushort_t* __restrict__ xfr,
                                                   const ushort_t* __restrict__ wifr,
                                                   const float* __restrict__ bi,
                                                   const ushort_t* __restrict__ wpfr,
                                                   const float* __restrict__ bp,
                                                   ushort_t* __restrict__ hbf,
                                                   ushort_t* __restrict__ qfr,
                                                   ushort_t* __restrict__ kfr,
                                                   ushort_t* __restrict__ vfr) {
    __shared__ __align__(16) ushort_t h_s[16][136];
    const int w = threadIdx.x >> 6, lane = threadIdx.x & 63;
    const int l15 = lane & 15, quad = lane >> 4;
    const int rt = blockIdx.x;
    const int r0 = rt * 16;

    // phase 1: 16 token rows; wave w owns output cols w*32..+31
    {
        bf16x8 af[4], bfr[2][4];
#pragma unroll
        for (int kf = 0; kf < 4; ++kf)
            af[kf] = *(const bf16x8*)(xfr + (((size_t)rt * 4 + kf) * 4 + quad) * 128 + l15 * 8);
#pragma unroll
        for (int nt = 0; nt < 2; ++nt)
#pragma unroll
            for (int kf = 0; kf < 4; ++kf)
                bfr[nt][kf] = *(const bf16x8*)(wifr + (((size_t)(w * 2 + nt) * 4 + kf) * 4 + quad) * 128 + l15 * 8);
#pragma unroll
        for (int nt = 0; nt < 2; ++nt) {
            float bias = bi[w * 32 + nt * 16 + l15];
            f32x4 c = {bias, bias, bias, bias};
#pragma unroll
            for (int kf = 0; kf < 4; ++kf)
                c = __builtin_amdgcn_mfma_f32_16x16x32_bf16(af[kf], bfr[nt][kf], c, 0, 0, 0);
            int col = w * 32 + nt * 16 + l15;
#pragma unroll
            for (int r = 0; r < 4; ++r) {
                int row = quad * 4 + r;
                short hv = f2bf(c[r]);
                h_s[row][col] = (ushort_t)hv;
                hbf[(size_t)(r0 + row) * 128 + col] = (ushort_t)hv;
            }
        }
    }
    __syncthreads();
    // phase 2: qkv; wave w owns output cols w*96..+95
    bf16x8 af2[4];
#pragma unroll
    for (int kf = 0; kf < 4; ++kf)
        af2[kf] = *(const bf16x8*)&h_s[l15][kf * 32 + quad * 8];
    const float QS = 0.25503482459918643f;  // log2e / sqrt(32)
#pragma unroll
    for (int nt = 0; nt < 6; ++nt) {
        const int n0 = w * 96 + nt * 16;
        bf16x8 bfr[4];
#pragma unroll
        for (int kf = 0; kf < 4; ++kf)
            bfr[kf] = *(const bf16x8*)(wpfr + (((size_t)(w * 6 + nt) * 4 + kf) * 4 + quad) * 128 + l15 * 8);
        float bias = bp[n0 + l15];
        f32x4 c = {bias, bias, bias, bias};
#pragma unroll
        for (int kf = 0; kf < 4; ++kf)
            c = __builtin_amdgcn_mfma_f32_16x16x32_bf16(af2[kf], bfr[kf], c, 0, 0, 0);
        if (n0 < 256) {  // Q or K -> generic frag order over [token][128]
            int col = (n0 < 128) ? (n0 + l15) : (n0 - 128 + l15);
            ushort_t* dstf = (n0 < 128) ? qfr : kfr;
            float sc = (n0 < 128) ? QS : 1.0f;
            int hh = col >> 5, qd = (col >> 3) & 3, j = col & 7;
#pragma unroll
            for (int r = 0; r < 4; ++r) {
                int token = r0 + quad * 4 + r;
                dstf[((((size_t)(token >> 4) * 4 + hh) * 4 + qd) * 16 + (token & 15)) * 8 + j] =
                    (ushort_t)f2bf(c[r] * sc);
            }
        } else {  // V -> B-operand frag order (keys along j), short4v store
            int d = n0 - 256 + l15;
            int hh = d >> 5, dt = (d >> 4) & 1, dl = d & 15;
            int key0 = r0 + quad * 4;
            int kb = key0 >> 5, qk = (key0 >> 3) & 3, j0 = key0 & 7;
            short4v pk = {f2bf(c[0]), f2bf(c[1]), f2bf(c[2]), f2bf(c[3])};
            *(short4v*)&vfr[(((((size_t)kb * 4 + hh) * 2 + dt) * 4 + qk) * 16 + dl) * 8 + j0] = pk;
        }
    }
}

// ---------- K2: flash attention partials ----------
// Wave = (32 q, head, quarter-K). Block = 4 head-waves; grid = 256 qt x 4 quarters
// (qt fast -> co-resident blocks share a K/V quarter in L2). All K/V/Q loads are
// coalesced 1KB fragment loads. Bias cooperatively staged (32x64 f32, dbuf, 3-deep
// register pipeline), sp read once device-wide. Lazy softmax-l (no per-iter l shfls).
__global__ __launch_bounds__(256, 3) void k_attn(const ushort_t* __restrict__ qfr,
                                                 const ushort_t* __restrict__ kfr,
                                                 const ushort_t* __restrict__ vfr,
                                                 const float* __restrict__ sp,
                                                 const float* __restrict__ scale_p,
                                                 ushort_t* __restrict__ pob,
                                                 float* __restrict__ pml) {
    __shared__ __align__(16) float bias_s[2][32][68];     // 17.4 KB
    __shared__ __align__(16) ushort_t p_s[4][2][16][72];  // 18.4 KB

    const int t = threadIdx.x;
    const int h = t >> 6;  // wave = head
    const int lane = t & 63, l15 = lane & 15, quad = lane >> 4;
    const int qt = blockIdx.x & 255;
    const int quarter = blockIdx.x >> 8;
    const int q0 = qt * 32;
    const int k0 = quarter * 2048;
    const float scale2 = scale_p[0] * 1.4426950408889634f;  // log2e folded

    // bias staging role: thread t covers sp row q0+(t>>3), cols (t&7)*8..+8
    const int brow = t >> 3, bc8 = (t & 7) * 8;
    const float* spb = sp + (size_t)(q0 + brow) * NROWS + k0 + bc8;

    // loop-invariant Q^T fragments (pre-scaled)
    bf16x8 bq[2];
#pragma unroll
    for (int qq = 0; qq < 2; ++qq)
        bq[qq] = *(const bf16x8*)(qfr + ((((size_t)(q0 >> 4) + qq) * 4 + h) * 4 + quad) * 128 + l15 * 8);

    // K/V fragment pipeline (1 tile ahead)
    bf16x8 af[4], vf[2][2];
#pragma unroll
    for (int c = 0; c < 4; ++c)
        af[c] = *(const bf16x8*)(kfr + ((((size_t)(k0 >> 4) + c) * 4 + h) * 4 + quad) * 128 + l15 * 8);
#pragma unroll
    for (int dt = 0; dt < 2; ++dt)
#pragma unroll
        for (int kc = 0; kc < 2; ++kc)
            vf[dt][kc] = *(const bf16x8*)(vfr + (((((size_t)(k0 >> 5) + kc) * 4 + h) * 2 + dt) * 4 + quad) * 128 + l15 * 8);

    // bias prologue: stage tile 0; fetch tiles 1,2 into regs
    {
        float4 a = *(const float4*)spb;
        float4 b = *(const float4*)(spb + 4);
        f32x4 ca = {bias_of(a.x, scale2), bias_of(a.y, scale2), bias_of(a.z, scale2), bias_of(a.w, scale2)};
        f32x4 cb = {bias_of(b.x, scale2), bias_of(b.y, scale2), bias_of(b.z, scale2), bias_of(b.w, scale2)};
        *(f32x4*)&bias_s[0][brow][bc8] = ca;
        *(f32x4*)&bias_s[0][brow][bc8 + 4] = cb;
    }
    float4 brg[2][2];
    brg[0][0] = *(const float4*)(spb + 64);
    brg[0][1] = *(const float4*)(spb + 68);
    brg[1][0] = *(const float4*)(spb + 128);
    brg[1][1] = *(const float4*)(spb + 132);
    __syncthreads();

    f32x4 oacc[2][2] = {};
    float m[2] = {-1e30f, -1e30f}, l[2] = {0.f, 0.f};

    for (int it = 0; it < 32; ++it) {
        const int cur = it & 1;
        // C-init from staged bias
        f32x4 sacc[4][2];
#pragma unroll
        for (int c = 0; c < 4; ++c)
#pragma unroll
            for (int qq = 0; qq < 2; ++qq)
                sacc[c][qq] = *(const f32x4*)&bias_s[cur][qq * 16 + l15][c * 16 + quad * 4];
        // QK^T (log2-domain scores)
#pragma unroll
        for (int c = 0; c < 4; ++c)
#pragma unroll
            for (int qq = 0; qq < 2; ++qq)
                sacc[c][qq] = __builtin_amdgcn_mfma_f32_16x16x32_bf16(af[c], bq[qq], sacc[c][qq], 0, 0, 0);
        // prefetch next K fragments
        if (it < 31) {
            size_t rtk = (size_t)(k0 >> 4) + (it + 1) * 4;
#pragma unroll
            for (int c = 0; c < 4; ++c)
                af[c] = *(const bf16x8*)(kfr + (((rtk + c) * 4 + h) * 4 + quad) * 128 + l15 * 8);
        }
        // online softmax per q-tile (2 shfls each; l stays per-lane)
#pragma unroll
        for (int qq = 0; qq < 2; ++qq) {
            float tmax = -1e30f;
#pragma unroll
            for (int c = 0; c < 4; ++c)
#pragma unroll
                for (int r = 0; r < 4; ++r) tmax = fmaxf(tmax, sacc[c][qq][r]);
            tmax = fmaxf(tmax, __shfl_xor(tmax, 16, 64));
            tmax = fmaxf(tmax, __shfl_xor(tmax, 32, 64));
            float mnew = fmaxf(m[qq], tmax);
            float alpha = exp2_fast(m[qq] - mnew);
            m[qq] = mnew;
            float lsum = 0.f;
#pragma unroll
            for (int c = 0; c < 4; ++c)
#pragma unroll
                for (int r = 0; r < 4; ++r) {
                    float p = exp2_fast(sacc[c][qq][r] - mnew);
                    sacc[c][qq][r] = p;
                    lsum += p;
                }
            l[qq] = l[qq] * alpha + lsum;
#pragma unroll
            for (int dt = 0; dt < 2; ++dt)
#pragma unroll
                for (int r = 0; r < 4; ++r) oacc[dt][qq][r] *= alpha;
        }
        // write P (truncating bf16 pack; P in (0,1])
#pragma unroll
        for (int qq = 0; qq < 2; ++qq)
#pragma unroll
            for (int c = 0; c < 4; ++c) {
                unsigned b0 = __float_as_uint(sacc[c][qq][0]);
                unsigned b1 = __float_as_uint(sacc[c][qq][1]);
                unsigned b2 = __float_as_uint(sacc[c][qq][2]);
                unsigned b3 = __float_as_uint(sacc[c][qq][3]);
                uint2 pw;
                pw.x = __builtin_amdgcn_perm(b1, b0, 0x07060302);
                pw.y = __builtin_amdgcn_perm(b3, b2, 0x07060302);
                *(uint2*)&p_s[h][qq][l15][c * 16 + quad * 4] = pw;
            }
        asm volatile("s_waitcnt lgkmcnt(0)" ::: "memory");  // same-wave P RAW
        bf16x8 pf[2][2];
#pragma unroll
        for (int qq = 0; qq < 2; ++qq)
#pragma unroll
            for (int kc = 0; kc < 2; ++kc)
                pf[qq][kc] = *(const bf16x8*)&p_s[h][qq][l15][kc * 32 + quad * 8];
        // PV: O^T += V^T . P^T
#pragma unroll
        for (int dt = 0; dt < 2; ++dt)
#pragma unroll
            for (int qq = 0; qq < 2; ++qq) {
                oacc[dt][qq] = __builtin_amdgcn_mfma_f32_16x16x32_bf16(vf[dt][0], pf[qq][0], oacc[dt][qq], 0, 0, 0);
                oacc[dt][qq] = __builtin_amdgcn_mfma_f32_16x16x32_bf16(vf[dt][1], pf[qq][1], oacc[dt][qq], 0, 0, 0);
            }
        // prefetch next V fragments
        if (it < 31) {
            size_t kb = (size_t)(k0 >> 5) + (it + 1) * 2;
#pragma unroll
            for (int dt = 0; dt < 2; ++dt)
#pragma unroll
                for (int kc = 0; kc < 2; ++kc)
                    vf[dt][kc] = *(const bf16x8*)(vfr + ((((kb + kc) * 4 + h) * 2 + dt) * 4 + quad) * 128 + l15 * 8);
        }
        // stage bias tile it+1 from regs; fetch tile it+3
        if (it < 31) {
            f32x4 ca = {bias_of(brg[cur][0].x, scale2), bias_of(brg[cur][0].y, scale2),
                        bias_of(brg[cur][0].z, scale2), bias_of(brg[cur][0].w, scale2)};
            f32x4 cb = {bias_of(brg[cur][1].x, scale2), bias_of(brg[cur][1].y, scale2),
                        bias_of(brg[cur][1].z, scale2), bias_of(brg[cur][1].w, scale2)};
            *(f32x4*)&bias_s[1 - cur][brow][bc8] = ca;
            *(f32x4*)&bias_s[1 - cur][brow][bc8 + 4] = cb;
            if (it < 29) {
                brg[cur][0] = *(const float4*)(spb + (it + 3) * 64);
                brg[cur][1] = *(const float4*)(spb + (it + 3) * 64 + 4);
            }
        }
        __syncthreads();
    }

    // epilogue: finish lazy-l reduce; store partials (bf16 O^T, f32 m/l)
#pragma unroll
    for (int qq = 0; qq < 2; ++qq) {
        float lt = l[qq];
        lt += __shfl_xor(lt, 16, 64);
        lt += __shfl_xor(lt, 32, 64);
        int q = q0 + qq * 16 + l15;
        size_t base = ((size_t)q * 4 + h) * 4 + quarter;
        if (quad == 0) {
            pml[base * 2 + 0] = m[qq];
            pml[base * 2 + 1] = lt;
        }
#pragma unroll
        for (int dt = 0; dt < 2; ++dt) {
            short4v pk = {f2bf(oacc[dt][qq][0]), f2bf(oacc[dt][qq][1]),
                          f2bf(oacc[dt][qq][2]), f2bf(oacc[dt][qq][3])};
            *(short4v*)&pob[base * 32 + dt * 16 + quad * 4] = pk;
        }
    }
}

// ---------- K3: merge 4 quarter-partials -> frag-ordered merged O (bf16) ----------
__global__ __launch_bounds__(256) void k_merge(const ushort_t* __restrict__ pob,
                                               const float* __restrict__ pml,
                                               ushort_t* __restrict__ obfr) {
    int gid = blockIdx.x * 256 + threadIdx.x;  // 131072 = 8192 q * 4 h * 4 dp
    int qh = gid >> 2;
    int dp = gid & 3;
    int q = qh >> 2, h = qh & 3;
    float4 ml01 = *(const float4*)(pml + (size_t)qh * 8);      // m0,l0,m1,l1
    float4 ml23 = *(const float4*)(pml + (size_t)qh * 8 + 4);  // m2,l2,m3,l3
    float mm = fmaxf(fmaxf(ml01.x, ml01.z), fmaxf(ml23.x, ml23.z));
    float a0 = exp2_fast(ml01.x - mm), a1 = exp2_fast(ml01.z - mm);
    float a2 = exp2_fast(ml23.x - mm), a3 = exp2_fast(ml23.z - mm);
    float linv = 1.f / (ml01.y * a0 + ml01.w * a1 + ml23.y * a2 + ml23.w * a3);
    a0 *= linv; a1 *= linv; a2 *= linv; a3 *= linv;
    float acc[8] = {};
    float aj[4] = {a0, a1, a2, a3};
#pragma unroll
    for (int j = 0; j < 4; ++j) {
        const ushort_t* p = pob + ((size_t)qh * 4 + j) * 32 + dp * 8;
        short4v v0 = *(const short4v*)p;
        short4v v1 = *(const short4v*)(p + 4);
#pragma unroll
        for (int e = 0; e < 4; ++e) {
            acc[e] += aj[j] * bf2f((ushort_t)v0[e]);
            acc[4 + e] += aj[j] * bf2f((ushort_t)v1[e]);
        }
    }
    // obfr[rt=q/16][h][quad=dp][l15=q%16][8]
    ushort_t* dst = obfr + ((((size_t)(q >> 4) * 4 + h) * 4 + dp) * 16 + (q & 15)) * 8;
    short4v s0 = {f2bf(acc[0]), f2bf(acc[1]), f2bf(acc[2]), f2bf(acc[3])};
    short4v s1 = {f2bf(acc[4]), f2bf(acc[5]), f2bf(acc[6]), f2bf(acc[7])};
    *(short4v*)dst = s0;
    *(short4v*)(dst + 4) = s1;
}

// ---------- K4: epilogue: out_proj -> relu+residual -> W_out -> log_softmax ----------
__global__ __launch_bounds__(256) void k_epi(const ushort_t* __restrict__ hbf,
                                             const ushort_t* __restrict__ obfr,
                                             const ushort_t* __restrict__ wofr,
                                             const float* __restrict__ bo,
                                             const ushort_t* __restrict__ woutfr,
                                             const float* __restrict__ bout,
                                             float* __restrict__ out) {
    __shared__ __align__(16) ushort_t hr_s[16][136];
    const int w = threadIdx.x >> 6, lane = threadIdx.x & 63;
    const int l15 = lane & 15, quad = lane >> 4;
    const int rt = blockIdx.x;
    const int r0 = rt * 16;

    // phase A: o2 = O @ Wo^T + bo -> relu -> +h -> hr_s (bf16)
    {
        bf16x8 af[4], bfr[2][4];
#pragma unroll
        for (int kf = 0; kf < 4; ++kf)
            af[kf] = *(const bf16x8*)(obfr + (((size_t)rt * 4 + kf) * 4 + quad) * 128 + l15 * 8);
#pragma unroll
        for (int nt = 0; nt < 2; ++nt)
#pragma unroll
            for (int kf = 0; kf < 4; ++kf)
                bfr[nt][kf] = *(const bf16x8*)(wofr + (((size_t)(w * 2 + nt) * 4 + kf) * 4 + quad) * 128 + l15 * 8);
#pragma unroll
        for (int nt = 0; nt < 2; ++nt) {
            float bias = bo[w * 32 + nt * 16 + l15];
            f32x4 c = {bias, bias, bias, bias};
#pragma unroll
            for (int kf = 0; kf < 4; ++kf)
                c = __builtin_amdgcn_mfma_f32_16x16x32_bf16(af[kf], bfr[nt][kf], c, 0, 0, 0);
            int col = w * 32 + nt * 16 + l15;
#pragma unroll
            for (int r = 0; r < 4; ++r) {
                int row = quad * 4 + r;
                float val = fmaxf(c[r], 0.f) + bf2f(hbf[(size_t)(r0 + row) * 128 + col]);
                hr_s[row][col] = (ushort_t)f2bf(val);
            }
        }
    }
    __syncthreads();
    // phase B (wave 0): logits^T = Wout . hr^T ; in-lane log_softmax per row
    if (w == 0) {
        f32x4 c[3];
#pragma unroll
        for (int mt = 0; mt < 3; ++mt)
#pragma unroll
            for (int r = 0; r < 4; ++r) {
                int oc = mt * 16 + quad * 4 + r;
                c[mt][r] = (oc < OUTC) ? bout[oc] : 0.f;
            }
#pragma unroll
        for (int kf = 0; kf < 4; ++kf) {
            bf16x8 bfrag = *(const bf16x8*)&hr_s[l15][kf * 32 + quad * 8];
#pragma unroll
            for (int mt = 0; mt < 3; ++mt) {
                bf16x8 afr = *(const bf16x8*)(woutfr + (((size_t)mt * 4 + kf) * 4 + quad) * 128 + l15 * 8);
                c[mt] = __builtin_amdgcn_mfma_f32_16x16x32_bf16(afr, bfrag, c[mt], 0, 0, 0);
            }
        }
        float mx = -1e30f;
#pragma unroll
        for (int mt = 0; mt < 3; ++mt)
#pragma unroll
            for (int r = 0; r < 4; ++r) {
                int oc = mt * 16 + quad * 4 + r;
                if (oc >= OUTC) c[mt][r] = -1e30f;
                mx = fmaxf(mx, c[mt][r]);
            }
        mx = fmaxf(mx, __shfl_xor(mx, 16, 64));
        mx = fmaxf(mx, __shfl_xor(mx, 32, 64));
        float ssum = 0.f;
#pragma unroll
        for (int mt = 0; mt < 3; ++mt)
#pragma unroll
            for (int r = 0; r < 4; ++r) ssum += __expf(c[mt][r] - mx);
        ssum += __shfl_xor(ssum, 16, 64);
        ssum += __shfl_xor(ssum, 32, 64);
        float lse = __logf(ssum) + mx;
        int row = r0 + l15;
#pragma unroll
        for (int mt = 0; mt < 2; ++mt) {
            float4 st = make_float4(c[mt][0] - lse, c[mt][1] - lse, c[mt][2] - lse, c[mt][3] - lse);
            *(float4*)(out + (size_t)row * OUTC + mt * 16 + quad * 4) = st;
        }
        if (quad < 2) {
            float4 st = make_float4(c[2][0] - lse, c[2][1] - lse, c[2][2] - lse, c[2][3] - lse);
            *(float4*)(out + (size_t)row * OUTC + 32 + quad * 4) = st;
        }
    }
}

extern "C" void kernel_launch(void* const* d_in, const int* in_sizes, int n_in,
                              void* d_out, int out_size, void* d_ws, size_t ws_size,
                              hipStream_t stream) {
    const float* x          = (const float*)d_in[0];
    // d_in[1] = pos_enc (unused in forward, faithful to reference)
    const float* sp         = (const float*)d_in[2];
    const float* W_in       = (const float*)d_in[3];
    const float* b_in       = (const float*)d_in[4];
    const float* in_proj_w  = (const float*)d_in[5];
    const float* in_proj_b  = (const float*)d_in[6];
    const float* out_proj_w = (const float*)d_in[7];
    const float* out_proj_b = (const float*)d_in[8];
    const float* W_out      = (const float*)d_in[9];
    const float* b_out      = (const float*)d_in[10];
    const float* scale      = (const float*)d_in[11];

    float*    pml    = (float*)d_ws;                        // 8192*4*4*2 f32 = 1 MiB
    ushort_t* pob    = (ushort_t*)(pml + (size_t)NROWS * 32);  // 8192*512 bf16 = 8 MiB
    ushort_t* xfr    = pob + (size_t)NROWS * 512;
    ushort_t* qfr    = xfr + (size_t)NROWS * 128;
    ushort_t* kfr    = qfr + (size_t)NROWS * 128;
    ushort_t* vfr    = kfr + (size_t)NROWS * 128;
    ushort_t* hbf    = vfr + (size_t)NROWS * 128;
    ushort_t* obfr   = hbf + (size_t)NROWS * 128;
    ushort_t* wifr   = obfr + (size_t)NROWS * 128;
    ushort_t* wpfr   = wifr + 128 * 128;
    ushort_t* wofr   = wpfr + 384 * 128;
    ushort_t* woutfr = wofr + 128 * 128;                    // 48*128 (zero-padded)
    float*    out    = (float*)d_out;

    hipLaunchKernelGGL(k_prep, dim3(555), dim3(256), 0, stream,
                       x, W_in, in_proj_w, out_proj_w, W_out, xfr, wifr, wpfr, wofr, woutfr);
    hipLaunchKernelGGL(k_qkv_fused, dim3(NROWS / 16), dim3(256), 0, stream,
                       xfr, wifr, b_in, wpfr, in_proj_b, hbf, qfr, kfr, vfr);
    hipLaunchKernelGGL(k_attn, dim3(256 * 4), dim3(256), 0, stream,
                       qfr, kfr, vfr, sp, scale, pob, pml);
    hipLaunchKernelGGL(k_merge, dim3(NROWS * 16 / 256), dim3(256), 0, stream,
                       pob, pml, obfr);
    hipLaunchKernelGGL(k_epi, dim3(NROWS / 16), dim3(256), 0, stream,
                       hbf, obfr, wofr, out_proj_b, woutfr, b_out, out);
}

// Round 9
// 520.201 us; speedup vs baseline: 1.7882x; 1.0306x over previous
//
#include <hip/hip_runtime.h>
#include <hip/hip_bf16.h>
#include <hip/hip_runtime_api.h>

// Problem constants
#define NROWS 8192
#define HID 128
#define OUTC 40

typedef unsigned short ushort_t;
typedef __attribute__((ext_vector_type(8))) short bf16x8;
typedef __attribute__((ext_vector_type(4))) short short4v;
typedef __attribute__((ext_vector_type(4))) float f32x4;

// f32 -> bf16 RNE
__device__ __forceinline__ short f2bf(float f) {
    unsigned int u = __float_as_uint(f);
    unsigned int r = (u + 0x7FFFu + ((u >> 16) & 1u)) >> 16;
    return (short)r;
}
__device__ __forceinline__ float bf2f(ushort_t b) {
    return __uint_as_float(((unsigned int)b) << 16);
}
__device__ __forceinline__ float exp2_fast(float x) {
#if __has_builtin(__builtin_amdgcn_exp2f)
    return __builtin_amdgcn_exp2f(x);
#else
    return exp2f(x);
#endif
}
// bias (log2 domain) with fixed softmax max M=16 folded in:
//   r = scale2/d - 16 ; d==0 (inf) or overflow -> -16.
// Scores s = bias + qk are bounded (bias <= ~14.4, |qk| small), so exp2(s-16)
// never overflows and softmax is shift-invariant -> exact same result, no
// running max / rescale needed, and split-K partials merge by PLAIN SUM.
__device__ __forceinline__ float bias_of16(float f, float scale2) {
    float r = scale2 * __builtin_amdgcn_rcpf(f);
    bool bad = (__float_as_uint(r) & 0x7F800000u) == 0x7F800000u;
    return bad ? -16.f : r - 16.f;
}

// Generic A-fragment tile layout over [rows][128 cols]:
//   frag[rt=row/16][kf=col/32][quad=(col%32)/8][l15=row%16][j=col%8]
// -> a wave's load for (rt,kf): base + ((rt*4+kf)*4+quad)*128 + l15*8 : 1KB contiguous.

// ---------- K0: one-time f32 -> frag-ordered bf16 (x + all weights) ----------
__global__ __launch_bounds__(256) void k_prep(const float* __restrict__ x,
                                              const float* __restrict__ Wi,
                                              const float* __restrict__ Wp,
                                              const float* __restrict__ Wo,
                                              const float* __restrict__ Wout,
                                              ushort_t* __restrict__ xfr,
                                              ushort_t* __restrict__ wifr,
                                              ushort_t* __restrict__ wpfr,
                                              ushort_t* __restrict__ wofr,
                                              ushort_t* __restrict__ woutfr) {
    int rb = blockIdx.x;
    const float* src; ushort_t* dst; int rt; int nrows;
    if (rb < 512)      { src = x;    dst = xfr;    rt = rb;       nrows = 1 << 30; }
    else if (rb < 520) { src = Wi;   dst = wifr;   rt = rb - 512; nrows = 1 << 30; }
    else if (rb < 544) { src = Wp;   dst = wpfr;   rt = rb - 520; nrows = 1 << 30; }
    else if (rb < 552) { src = Wo;   dst = wofr;   rt = rb - 544; nrows = 1 << 30; }
    else               { src = Wout; dst = woutfr; rt = rb - 552; nrows = OUTC; }  // pad to 48 rows
    int t = threadIdx.x;
    int r = t >> 4, c8 = t & 15;
    int row = rt * 16 + r;
    float4 a = {0.f, 0.f, 0.f, 0.f}, b = {0.f, 0.f, 0.f, 0.f};
    if (row < nrows) {
        a = *(const float4*)(src + (size_t)row * 128 + c8 * 8);
        b = *(const float4*)(src + (size_t)row * 128 + c8 * 8 + 4);
    }
    short4v s0 = {f2bf(a.x), f2bf(a.y), f2bf(a.z), f2bf(a.w)};
    short4v s1 = {f2bf(b.x), f2bf(b.y), f2bf(b.z), f2bf(b.w)};
    ushort_t* d = dst + ((((size_t)rt * 4 + (c8 >> 2)) * 4 + (c8 & 3)) * 16 + r) * 8;
    *(short4v*)d = s0;
    *(short4v*)(d + 4) = s1;
}

// ---------- K1: fused h = x@Wi^T+bi -> qkv = h@Wp^T+bp (frag-ordered in/out) ----------
__global__ __launch_bounds__(256) void k_qkv_fused(const ushort_t* __restrict__ xfr,
                                                   const ushort_t* __restrict__ wifr,
                                                   const float* __restrict__ bi,
                                                   const ushort_t* __restrict__ wpfr,
                                                   const float* __restrict__ bp,
                                                   ushort_t* __restrict__ hbf,
                                                   ushort_t* __restrict__ qfr,
                                                   ushort_t* __restrict__ kfr,
                                                   ushort_t* __restrict__ vfr) {
    __shared__ __align__(16) ushort_t h_s[16][136];
    const int w = threadIdx.x >> 6, lane = threadIdx.x & 63;
    const int l15 = lane & 15, quad = lane >> 4;
    const int rt = blockIdx.x;
    const int r0 = rt * 16;

    // phase 1: 16 token rows; wave w owns output cols w*32..+31
    {
        bf16x8 af[4], bfr[2][4];
#pragma unroll
        for (int kf = 0; kf < 4; ++kf)
            af[kf] = *(const bf16x8*)(xfr + (((size_t)rt * 4 + kf) * 4 + quad) * 128 + l15 * 8);
#pragma unroll
        for (int nt = 0; nt < 2; ++nt)
#pragma unroll
            for (int kf = 0; kf < 4; ++kf)
                bfr[nt][kf] = *(const bf16x8*)(wifr + (((size_t)(w * 2 + nt) * 4 + kf) * 4 + quad) * 128 + l15 * 8);
#pragma unroll
        for (int nt = 0; nt < 2; ++nt) {
            float bias = bi[w * 32 + nt * 16 + l15];
            f32x4 c = {bias, bias, bias, bias};
#pragma unroll
            for (int kf = 0; kf < 4; ++kf)
                c = __builtin_amdgcn_mfma_f32_16x16x32_bf16(af[kf], bfr[nt][kf], c, 0, 0, 0);
            int col = w * 32 + nt * 16 + l15;
#pragma unroll
            for (int r = 0; r < 4; ++r) {
                int row = quad * 4 + r;
                short hv = f2bf(c[r]);
                h_s[row][col] = (ushort_t)hv;
                hbf[(size_t)(r0 + row) * 128 + col] = (ushort_t)hv;
            }
        }
    }
    __syncthreads();
    // phase 2: qkv; wave w owns output cols w*96..+95
    bf16x8 af2[4];
#pragma unroll
    for (int kf = 0; kf < 4; ++kf)
        af2[kf] = *(const bf16x8*)&h_s[l15][kf * 32 + quad * 8];
    const float QS = 0.25503482459918643f;  // log2e / sqrt(32)
#pragma unroll
    for (int nt = 0; nt < 6; ++nt) {
        const int n0 = w * 96 + nt * 16;
        bf16x8 bfr[4];
#pragma unroll
        for (int kf = 0; kf < 4; ++kf)
            bfr[kf] = *(const bf16x8*)(wpfr + (((size_t)(w * 6 + nt) * 4 + kf) * 4 + quad) * 128 + l15 * 8);
        float bias = bp[n0 + l15];
        f32x4 c = {bias, bias, bias, bias};
#pragma unroll
        for (int kf = 0; kf < 4; ++kf)
            c = __builtin_amdgcn_mfma_f32_16x16x32_bf16(af2[kf], bfr[kf], c, 0, 0, 0);
        if (n0 < 256) {  // Q or K -> generic frag order over [token][128]
            int col = (n0 < 128) ? (n0 + l15) : (n0 - 128 + l15);
            ushort_t* dstf = (n0 < 128) ? qfr : kfr;
            float sc = (n0 < 128) ? QS : 1.0f;
            int hh = col >> 5, qd = (col >> 3) & 3, j = col & 7;
#pragma unroll
            for (int r = 0; r < 4; ++r) {
                int token = r0 + quad * 4 + r;
                dstf[((((size_t)(token >> 4) * 4 + hh) * 4 + qd) * 16 + (token & 15)) * 8 + j] =
                    (ushort_t)f2bf(c[r] * sc);
            }
        } else {  // V -> B-operand frag order (keys along j), short4v store
            int d = n0 - 256 + l15;
            int hh = d >> 5, dt = (d >> 4) & 1, dl = d & 15;
            int key0 = r0 + quad * 4;
            int kb = key0 >> 5, qk = (key0 >> 3) & 3, j0 = key0 & 7;
            short4v pk = {f2bf(c[0]), f2bf(c[1]), f2bf(c[2]), f2bf(c[3])};
            *(short4v*)&vfr[(((((size_t)kb * 4 + hh) * 2 + dt) * 4 + qk) * 16 + dl) * 8 + j0] = pk;
        }
    }
}

// ---------- K2: flash attention partials (fixed-max softmax, no merge math) ----------
// Wave = (32 q, head, quarter-K). Bias cooperatively staged (sp read once device-wide).
// p = exp2(bias - 16 + qk): no running max, no alpha rescale, no cross-lane ops in loop.
// Partials: pob (unnormalized O^T sum, bf16), pml (l sums) -> merged by plain sum in k_epi.
__global__ __launch_bounds__(256, 4) void k_attn(const ushort_t* __restrict__ qfr,
                                                 const ushort_t* __restrict__ kfr,
                                                 const ushort_t* __restrict__ vfr,
                                                 const float* __restrict__ sp,
                                                 const float* __restrict__ scale_p,
                                                 ushort_t* __restrict__ pob,
                                                 float* __restrict__ pml) {
    __shared__ __align__(16) float bias_s[2][32][68];     // 17.4 KB
    __shared__ __align__(16) ushort_t p_s[4][2][16][72];  // 18.4 KB

    const int t = threadIdx.x;
    const int h = t >> 6;  // wave = head
    const int lane = t & 63, l15 = lane & 15, quad = lane >> 4;
    const int qt = blockIdx.x & 255;
    const int quarter = blockIdx.x >> 8;
    const int q0 = qt * 32;
    const int k0 = quarter * 2048;
    const float scale2 = scale_p[0] * 1.4426950408889634f;  // log2e folded

    // bias staging role: thread t covers sp row q0+(t>>3), cols (t&7)*8..+8
    const int brow = t >> 3, bc8 = (t & 7) * 8;
    const float* spb = sp + (size_t)(q0 + brow) * NROWS + k0 + bc8;

    // loop-invariant Q^T fragments (pre-scaled)
    bf16x8 bq[2];
#pragma unroll
    for (int qq = 0; qq < 2; ++qq)
        bq[qq] = *(const bf16x8*)(qfr + ((((size_t)(q0 >> 4) + qq) * 4 + h) * 4 + quad) * 128 + l15 * 8);

    // K/V fragment pipeline (1 tile ahead)
    bf16x8 af[4], vf[2][2];
#pragma unroll
    for (int c = 0; c < 4; ++c)
        af[c] = *(const bf16x8*)(kfr + ((((size_t)(k0 >> 4) + c) * 4 + h) * 4 + quad) * 128 + l15 * 8);
#pragma unroll
    for (int dt = 0; dt < 2; ++dt)
#pragma unroll
        for (int kc = 0; kc < 2; ++kc)
            vf[dt][kc] = *(const bf16x8*)(vfr + (((((size_t)(k0 >> 5) + kc) * 4 + h) * 2 + dt) * 4 + quad) * 128 + l15 * 8);

    // bias prologue: stage tile 0; fetch tiles 1,2 into regs
    {
        float4 a = *(const float4*)spb;
        float4 b = *(const float4*)(spb + 4);
        f32x4 ca = {bias_of16(a.x, scale2), bias_of16(a.y, scale2), bias_of16(a.z, scale2), bias_of16(a.w, scale2)};
        f32x4 cb = {bias_of16(b.x, scale2), bias_of16(b.y, scale2), bias_of16(b.z, scale2), bias_of16(b.w, scale2)};
        *(f32x4*)&bias_s[0][brow][bc8] = ca;
        *(f32x4*)&bias_s[0][brow][bc8 + 4] = cb;
    }
    float4 brg[2][2];
    brg[0][0] = *(const float4*)(spb + 64);
    brg[0][1] = *(const float4*)(spb + 68);
    brg[1][0] = *(const float4*)(spb + 128);
    brg[1][1] = *(const float4*)(spb + 132);
    __syncthreads();

    f32x4 oacc[2][2] = {};
    float l[2] = {0.f, 0.f};

    for (int it = 0; it < 32; ++it) {
        const int cur = it & 1;
        // C-init from staged (bias - 16)
        f32x4 sacc[4][2];
#pragma unroll
        for (int c = 0; c < 4; ++c)
#pragma unroll
            for (int qq = 0; qq < 2; ++qq)
                sacc[c][qq] = *(const f32x4*)&bias_s[cur][qq * 16 + l15][c * 16 + quad * 4];
        // QK^T (log2-domain scores, pre-shifted by -16)
#pragma unroll
        for (int c = 0; c < 4; ++c)
#pragma unroll
            for (int qq = 0; qq < 2; ++qq)
                sacc[c][qq] = __builtin_amdgcn_mfma_f32_16x16x32_bf16(af[c], bq[qq], sacc[c][qq], 0, 0, 0);
        // prefetch next K fragments
        if (it < 31) {
            size_t rtk = (size_t)(k0 >> 4) + (it + 1) * 4;
#pragma unroll
            for (int c = 0; c < 4; ++c)
                af[c] = *(const bf16x8*)(kfr + (((rtk + c) * 4 + h) * 4 + quad) * 128 + l15 * 8);
        }
        // p = exp2(s); accumulate l per-lane (no max, no rescale, no shfl)
#pragma unroll
        for (int qq = 0; qq < 2; ++qq) {
            float lsum = 0.f;
#pragma unroll
            for (int c = 0; c < 4; ++c)
#pragma unroll
                for (int r = 0; r < 4; ++r) {
                    float p = exp2_fast(sacc[c][qq][r]);
                    sacc[c][qq][r] = p;
                    lsum += p;
                }
            l[qq] += lsum;
        }
        // write P (truncating bf16 pack; p in (0, ~0.35])
#pragma unroll
        for (int qq = 0; qq < 2; ++qq)
#pragma unroll
            for (int c = 0; c < 4; ++c) {
                unsigned b0 = __float_as_uint(sacc[c][qq][0]);
                unsigned b1 = __float_as_uint(sacc[c][qq][1]);
                unsigned b2 = __float_as_uint(sacc[c][qq][2]);
                unsigned b3 = __float_as_uint(sacc[c][qq][3]);
                uint2 pw;
                pw.x = __builtin_amdgcn_perm(b1, b0, 0x07060302);
                pw.y = __builtin_amdgcn_perm(b3, b2, 0x07060302);
                *(uint2*)&p_s[h][qq][l15][c * 16 + quad * 4] = pw;
            }
        asm volatile("s_waitcnt lgkmcnt(0)" ::: "memory");  // same-wave P RAW
        bf16x8 pf[2][2];
#pragma unroll
        for (int qq = 0; qq < 2; ++qq)
#pragma unroll
            for (int kc = 0; kc < 2; ++kc)
                pf[qq][kc] = *(const bf16x8*)&p_s[h][qq][l15][kc * 32 + quad * 8];
        // PV: O^T += V^T . P^T
#pragma unroll
        for (int dt = 0; dt < 2; ++dt)
#pragma unroll
            for (int qq = 0; qq < 2; ++qq) {
                oacc[dt][qq] = __builtin_amdgcn_mfma_f32_16x16x32_bf16(vf[dt][0], pf[qq][0], oacc[dt][qq], 0, 0, 0);
                oacc[dt][qq] = __builtin_amdgcn_mfma_f32_16x16x32_bf16(vf[dt][1], pf[qq][1], oacc[dt][qq], 0, 0, 0);
            }
        // prefetch next V fragments
        if (it < 31) {
            size_t kb = (size_t)(k0 >> 5) + (it + 1) * 2;
#pragma unroll
            for (int dt = 0; dt < 2; ++dt)
#pragma unroll
                for (int kc = 0; kc < 2; ++kc)
                    vf[dt][kc] = *(const bf16x8*)(vfr + ((((kb + kc) * 4 + h) * 2 + dt) * 4 + quad) * 128 + l15 * 8);
        }
        // stage bias tile it+1 from regs; fetch tile it+3
        if (it < 31) {
            f32x4 ca = {bias_of16(brg[cur][0].x, scale2), bias_of16(brg[cur][0].y, scale2),
                        bias_of16(brg[cur][0].z, scale2), bias_of16(brg[cur][0].w, scale2)};
            f32x4 cb = {bias_of16(brg[cur][1].x, scale2), bias_of16(brg[cur][1].y, scale2),
                        bias_of16(brg[cur][1].z, scale2), bias_of16(brg[cur][1].w, scale2)};
            *(f32x4*)&bias_s[1 - cur][brow][bc8] = ca;
            *(f32x4*)&bias_s[1 - cur][brow][bc8 + 4] = cb;
            if (it < 29) {
                brg[cur][0] = *(const float4*)(spb + (it + 3) * 64);
                brg[cur][1] = *(const float4*)(spb + (it + 3) * 64 + 4);
            }
        }
        __syncthreads();
    }

    // epilogue: reduce l across quads; store partials
    // pob layout: [qtile][h][quarter][dt][quad][l15][4] -> lane store = 8B, wave = 512B contig
#pragma unroll
    for (int qq = 0; qq < 2; ++qq) {
        float lt = l[qq];
        lt += __shfl_xor(lt, 16, 64);
        lt += __shfl_xor(lt, 32, 64);
        int qtile = qt * 2 + qq;
        if (quad == 0)
            pml[((size_t)(q0 + qq * 16 + l15) * 4 + h) * 4 + quarter] = lt;
#pragma unroll
        for (int dt = 0; dt < 2; ++dt) {
            short4v pk = {f2bf(oacc[dt][qq][0]), f2bf(oacc[dt][qq][1]),
                          f2bf(oacc[dt][qq][2]), f2bf(oacc[dt][qq][3])};
            *(short4v*)&pob[(((((size_t)qtile * 4 + h) * 4 + quarter) * 2 + dt) * 256)
                            + quad * 64 + l15 * 4] = pk;
        }
    }
}

// ---------- K3: epilogue (partial-sum merge + out_proj -> relu+residual -> W_out -> log_softmax) ----------
__global__ __launch_bounds__(256) void k_epi(const ushort_t* __restrict__ hbf,
                                             const ushort_t* __restrict__ pob,
                                             const float* __restrict__ pml,
                                             const ushort_t* __restrict__ wofr,
                                             const float* __restrict__ bo,
                                             const ushort_t* __restrict__ woutfr,
                                             const float* __restrict__ bout,
                                             float* __restrict__ out) {
    __shared__ __align__(16) ushort_t hr_s[16][136];
    const int w = threadIdx.x >> 6, lane = threadIdx.x & 63;
    const int l15 = lane & 15, quad = lane >> 4;
    const int rt = blockIdx.x;
    const int r0 = rt * 16;

    // phase A: merge 4 quarter-partials (plain sum; fixed-max softmax) -> A-frags;
    // o2 = O @ Wo^T + bo -> relu -> +h -> hr_s (bf16)
    {
        bf16x8 af[4], bfr[2][4];
#pragma unroll
        for (int kf = 0; kf < 4; ++kf) {
            float4 lv = *(const float4*)(pml + ((size_t)(r0 + l15) * 4 + kf) * 4);
            float linv = 1.f / (lv.x + lv.y + lv.z + lv.w);
            float acc[8] = {0.f, 0.f, 0.f, 0.f, 0.f, 0.f, 0.f, 0.f};
#pragma unroll
            for (int j = 0; j < 4; ++j) {
                size_t base = ((((size_t)rt * 4 + kf) * 4 + j) * 2 + (quad >> 1)) * 256
                              + (quad & 1) * 128 + l15 * 4;
                short4v v0 = *(const short4v*)(pob + base);
                short4v v1 = *(const short4v*)(pob + base + 64);
#pragma unroll
                for (int e = 0; e < 4; ++e) {
                    acc[e] += bf2f((ushort_t)v0[e]);
                    acc[4 + e] += bf2f((ushort_t)v1[e]);
                }
            }
            bf16x8 a;
#pragma unroll
            for (int e = 0; e < 8; ++e) a[e] = f2bf(acc[e] * linv);
            af[kf] = a;
        }
#pragma unroll
        for (int nt = 0; nt < 2; ++nt)
#pragma unroll
            for (int kf = 0; kf < 4; ++kf)
                bfr[nt][kf] = *(const bf16x8*)(wofr + (((size_t)(w * 2 + nt) * 4 + kf) * 4 + quad) * 128 + l15 * 8);
#pragma unroll
        for (int nt = 0; nt < 2; ++nt) {
            float bias = bo[w * 32 + nt * 16 + l15];
            f32x4 c = {bias, bias, bias, bias};
#pragma unroll
            for (int kf = 0; kf < 4; ++kf)
                c = __builtin_amdgcn_mfma_f32_16x16x32_bf16(af[kf], bfr[nt][kf], c, 0, 0, 0);
            int col = w * 32 + nt * 16 + l15;
#pragma unroll
            for (int r = 0; r < 4; ++r) {
                int row = quad * 4 + r;
                float val = fmaxf(c[r], 0.f) + bf2f(hbf[(size_t)(r0 + row) * 128 + col]);
                hr_s[row][col] = (ushort_t)f2bf(val);
            }
        }
    }
    __syncthreads();
    // phase B (wave 0): logits^T = Wout . hr^T ; in-lane log_softmax per row
    if (w == 0) {
        f32x4 c[3];
#pragma unroll
        for (int mt = 0; mt < 3; ++mt)
#pragma unroll
            for (int r = 0; r < 4; ++r) {
                int oc = mt * 16 + quad * 4 + r;
                c[mt][r] = (oc < OUTC) ? bout[oc] : 0.f;
            }
#pragma unroll
        for (int kf = 0; kf < 4; ++kf) {
            bf16x8 bfrag = *(const bf16x8*)&hr_s[l15][kf * 32 + quad * 8];
#pragma unroll
            for (int mt = 0; mt < 3; ++mt) {
                bf16x8 afr = *(const bf16x8*)(woutfr + (((size_t)mt * 4 + kf) * 4 + quad) * 128 + l15 * 8);
                c[mt] = __builtin_amdgcn_mfma_f32_16x16x32_bf16(afr, bfrag, c[mt], 0, 0, 0);
            }
        }
        float mx = -1e30f;
#pragma unroll
        for (int mt = 0; mt < 3; ++mt)
#pragma unroll
            for (int r = 0; r < 4; ++r) {
                int oc = mt * 16 + quad * 4 + r;
                if (oc >= OUTC) c[mt][r] = -1e30f;
                mx = fmaxf(mx, c[mt][r]);
            }
        mx = fmaxf(mx, __shfl_xor(mx, 16, 64));
        mx = fmaxf(mx, __shfl_xor(mx, 32, 64));
        float ssum = 0.f;
#pragma unroll
        for (int mt = 0; mt < 3; ++mt)
#pragma unroll
            for (int r = 0; r < 4; ++r) ssum += __expf(c[mt][r] - mx);
        ssum += __shfl_xor(ssum, 16, 64);
        ssum += __shfl_xor(ssum, 32, 64);
        float lse = __logf(ssum) + mx;
        int row = r0 + l15;
#pragma unroll
        for (int mt = 0; mt < 2; ++mt) {
            float4 st = make_float4(c[mt][0] - lse, c[mt][1] - lse, c[mt][2] - lse, c[mt][3] - lse);
            *(float4*)(out + (size_t)row * OUTC + mt * 16 + quad * 4) = st;
        }
        if (quad < 2) {
            float4 st = make_float4(c[2][0] - lse, c[2][1] - lse, c[2][2] - lse, c[2][3] - lse);
            *(float4*)(out + (size_t)row * OUTC + 32 + quad * 4) = st;
        }
    }
}

extern "C" void kernel_launch(void* const* d_in, const int* in_sizes, int n_in,
                              void* d_out, int out_size, void* d_ws, size_t ws_size,
                              hipStream_t stream) {
    const float* x          = (const float*)d_in[0];
    // d_in[1] = pos_enc (unused in forward, faithful to reference)
    const float* sp         = (const float*)d_in[2];
    const float* W_in       = (const float*)d_in[3];
    const float* b_in       = (const float*)d_in[4];
    const float* in_proj_w  = (const float*)d_in[5];
    const float* in_proj_b  = (const float*)d_in[6];
    const float* out_proj_w = (const float*)d_in[7];
    const float* out_proj_b = (const float*)d_in[8];
    const float* W_out      = (const float*)d_in[9];
    const float* b_out      = (const float*)d_in[10];
    const float* scale      = (const float*)d_in[11];

    float*    pml    = (float*)d_ws;                           // 8192*16 f32 = 512 KiB
    ushort_t* pob    = (ushort_t*)(pml + (size_t)NROWS * 16);  // 8 MiB bf16 partial O
    ushort_t* xfr    = pob + (size_t)NROWS * 512;
    ushort_t* qfr    = xfr + (size_t)NROWS * 128;
    ushort_t* kfr    = qfr + (size_t)NROWS * 128;
    ushort_t* vfr    = kfr + (size_t)NROWS * 128;
    ushort_t* hbf    = vfr + (size_t)NROWS * 128;
    ushort_t* wifr   = hbf + (size_t)NROWS * 128;
    ushort_t* wpfr   = wifr + 128 * 128;
    ushort_t* wofr   = wpfr + 384 * 128;
    ushort_t* woutfr = wofr + 128 * 128;                       // 48*128 (zero-padded)
    float*    out    = (float*)d_out;

    hipLaunchKernelGGL(k_prep, dim3(555), dim3(256), 0, stream,
                       x, W_in, in_proj_w, out_proj_w, W_out, xfr, wifr, wpfr, wofr, woutfr);
    hipLaunchKernelGGL(k_qkv_fused, dim3(NROWS / 16), dim3(256), 0, stream,
                       xfr, wifr, b_in, wpfr, in_proj_b, hbf, qfr, kfr, vfr);
    hipLaunchKernelGGL(k_attn, dim3(256 * 4), dim3(256), 0, stream,
                       qfr, kfr, vfr, sp, scale, pob, pml);
    hipLaunchKernelGGL(k_epi, dim3(NROWS / 16), dim3(256), 0, stream,
                       hbf, pob, pml, wofr, out_proj_b, woutfr, b_out, out);
}

// Round 10
// 483.879 us; speedup vs baseline: 1.9225x; 1.0751x over previous
//
#include <hip/hip_runtime.h>
#include <hip/hip_bf16.h>
#include <hip/hip_runtime_api.h>

// Problem constants
#define NROWS 8192
#define HID 128
#define OUTC 40

typedef unsigned short ushort_t;
typedef __attribute__((ext_vector_type(8))) short bf16x8;
typedef __attribute__((ext_vector_type(4))) short short4v;
typedef __attribute__((ext_vector_type(4))) float f32x4;

// f32 -> bf16 RNE
__device__ __forceinline__ short f2bf(float f) {
    unsigned int u = __float_as_uint(f);
    unsigned int r = (u + 0x7FFFu + ((u >> 16) & 1u)) >> 16;
    return (short)r;
}
__device__ __forceinline__ float bf2f(ushort_t b) {
    return __uint_as_float(((unsigned int)b) << 16);
}
__device__ __forceinline__ float exp2_fast(float x) {
#if __has_builtin(__builtin_amdgcn_exp2f)
    return __builtin_amdgcn_exp2f(x);
#else
    return exp2f(x);
#endif
}
// bias (log2 domain) with fixed softmax max M=16 folded in:
//   r = scale2/d - 16 ; d==0 (inf) or overflow -> -16.
// Scores s = bias + qk bounded above by ~-1.5 -> exp2(s) never overflows;
// softmax shift-invariant -> identical result, split-K partials merge by plain sum.
__device__ __forceinline__ float bias_of16(float f, float scale2) {
    float r = scale2 * __builtin_amdgcn_rcpf(f);
    bool bad = (__float_as_uint(r) & 0x7F800000u) == 0x7F800000u;
    return bad ? -16.f : r - 16.f;
}

// Generic A-fragment tile layout over [rows][128 cols]:
//   frag[rt=row/16][kf=col/32][quad=(col%32)/8][l15=row%16][j=col%8]
// -> a wave's load for (rt,kf): base + ((rt*4+kf)*4+quad)*128 + l15*8 : 1KB contiguous.

// ---------- K0: one-time f32 -> frag-ordered bf16 (x + all weights) ----------
__global__ __launch_bounds__(256) void k_prep(const float* __restrict__ x,
                                              const float* __restrict__ Wi,
                                              const float* __restrict__ Wp,
                                              const float* __restrict__ Wo,
                                              const float* __restrict__ Wout,
                                              ushort_t* __restrict__ xfr,
                                              ushort_t* __restrict__ wifr,
                                              ushort_t* __restrict__ wpfr,
                                              ushort_t* __restrict__ wofr,
                                              ushort_t* __restrict__ woutfr) {
    int rb = blockIdx.x;
    const float* src; ushort_t* dst; int rt; int nrows;
    if (rb < 512)      { src = x;    dst = xfr;    rt = rb;       nrows = 1 << 30; }
    else if (rb < 520) { src = Wi;   dst = wifr;   rt = rb - 512; nrows = 1 << 30; }
    else if (rb < 544) { src = Wp;   dst = wpfr;   rt = rb - 520; nrows = 1 << 30; }
    else if (rb < 552) { src = Wo;   dst = wofr;   rt = rb - 544; nrows = 1 << 30; }
    else               { src = Wout; dst = woutfr; rt = rb - 552; nrows = OUTC; }  // pad to 48 rows
    int t = threadIdx.x;
    int r = t >> 4, c8 = t & 15;
    int row = rt * 16 + r;
    float4 a = {0.f, 0.f, 0.f, 0.f}, b = {0.f, 0.f, 0.f, 0.f};
    if (row < nrows) {
        a = *(const float4*)(src + (size_t)row * 128 + c8 * 8);
        b = *(const float4*)(src + (size_t)row * 128 + c8 * 8 + 4);
    }
    short4v s0 = {f2bf(a.x), f2bf(a.y), f2bf(a.z), f2bf(a.w)};
    short4v s1 = {f2bf(b.x), f2bf(b.y), f2bf(b.z), f2bf(b.w)};
    ushort_t* d = dst + ((((size_t)rt * 4 + (c8 >> 2)) * 4 + (c8 & 3)) * 16 + r) * 8;
    *(short4v*)d = s0;
    *(short4v*)(d + 4) = s1;
}

// ---------- K1: fused h = x@Wi^T+bi -> qkv = h@Wp^T+bp (frag-ordered in/out) ----------
__global__ __launch_bounds__(256) void k_qkv_fused(const ushort_t* __restrict__ xfr,
                                                   const ushort_t* __restrict__ wifr,
                                                   const float* __restrict__ bi,
                                                   const ushort_t* __restrict__ wpfr,
                                                   const float* __restrict__ bp,
                                                   ushort_t* __restrict__ hbf,
                                                   ushort_t* __restrict__ qfr,
                                                   ushort_t* __restrict__ kfr,
                                                   ushort_t* __restrict__ vfr) {
    __shared__ __align__(16) ushort_t h_s[16][136];
    const int w = threadIdx.x >> 6, lane = threadIdx.x & 63;
    const int l15 = lane & 15, quad = lane >> 4;
    const int rt = blockIdx.x;
    const int r0 = rt * 16;

    // phase 1: 16 token rows; wave w owns output cols w*32..+31
    {
        bf16x8 af[4], bfr[2][4];
#pragma unroll
        for (int kf = 0; kf < 4; ++kf)
            af[kf] = *(const bf16x8*)(xfr + (((size_t)rt * 4 + kf) * 4 + quad) * 128 + l15 * 8);
#pragma unroll
        for (int nt = 0; nt < 2; ++nt)
#pragma unroll
            for (int kf = 0; kf < 4; ++kf)
                bfr[nt][kf] = *(const bf16x8*)(wifr + (((size_t)(w * 2 + nt) * 4 + kf) * 4 + quad) * 128 + l15 * 8);
#pragma unroll
        for (int nt = 0; nt < 2; ++nt) {
            float bias = bi[w * 32 + nt * 16 + l15];
            f32x4 c = {bias, bias, bias, bias};
#pragma unroll
            for (int kf = 0; kf < 4; ++kf)
                c = __builtin_amdgcn_mfma_f32_16x16x32_bf16(af[kf], bfr[nt][kf], c, 0, 0, 0);
            int col = w * 32 + nt * 16 + l15;
#pragma unroll
            for (int r = 0; r < 4; ++r) {
                int row = quad * 4 + r;
                short hv = f2bf(c[r]);
                h_s[row][col] = (ushort_t)hv;
                hbf[(size_t)(r0 + row) * 128 + col] = (ushort_t)hv;
            }
        }
    }
    __syncthreads();
    // phase 2: qkv; wave w owns output cols w*96..+95
    bf16x8 af2[4];
#pragma unroll
    for (int kf = 0; kf < 4; ++kf)
        af2[kf] = *(const bf16x8*)&h_s[l15][kf * 32 + quad * 8];
    const float QS = 0.25503482459918643f;  // log2e / sqrt(32)
#pragma unroll
    for (int nt = 0; nt < 6; ++nt) {
        const int n0 = w * 96 + nt * 16;
        bf16x8 bfr[4];
#pragma unroll
        for (int kf = 0; kf < 4; ++kf)
            bfr[kf] = *(const bf16x8*)(wpfr + (((size_t)(w * 6 + nt) * 4 + kf) * 4 + quad) * 128 + l15 * 8);
        float bias = bp[n0 + l15];
        f32x4 c = {bias, bias, bias, bias};
#pragma unroll
        for (int kf = 0; kf < 4; ++kf)
            c = __builtin_amdgcn_mfma_f32_16x16x32_bf16(af2[kf], bfr[kf], c, 0, 0, 0);
        if (n0 < 256) {  // Q or K -> generic frag order over [token][128]
            int col = (n0 < 128) ? (n0 + l15) : (n0 - 128 + l15);
            ushort_t* dstf = (n0 < 128) ? qfr : kfr;
            float sc = (n0 < 128) ? QS : 1.0f;
            int hh = col >> 5, qd = (col >> 3) & 3, j = col & 7;
#pragma unroll
            for (int r = 0; r < 4; ++r) {
                int token = r0 + quad * 4 + r;
                dstf[((((size_t)(token >> 4) * 4 + hh) * 4 + qd) * 16 + (token & 15)) * 8 + j] =
                    (ushort_t)f2bf(c[r] * sc);
            }
        } else {  // V -> B-operand frag order (keys along j), short4v store
            int d = n0 - 256 + l15;
            int hh = d >> 5, dt = (d >> 4) & 1, dl = d & 15;
            int key0 = r0 + quad * 4;
            int kb = key0 >> 5, qk = (key0 >> 3) & 3, j0 = key0 & 7;
            short4v pk = {f2bf(c[0]), f2bf(c[1]), f2bf(c[2]), f2bf(c[3])};
            *(short4v*)&vfr[(((((size_t)kb * 4 + hh) * 2 + dt) * 4 + qk) * 16 + dl) * 8 + j0] = pk;
        }
    }
}

// ---------- K2: flash attention partials (fixed-max softmax) ----------
// Wave = (32 q, head, K-half). Bias staged in ROUNDS of 4 tiles (32x256 f32 super-tile):
// per row 1KB contiguous per round (DRAM-friendly), nontemporal (zero reuse), single
// 33KB LDS buffer, 2 barriers per 4 iters. Register pipeline = 1 round deep.
__global__ __launch_bounds__(256, 2) void k_attn(const ushort_t* __restrict__ qfr,
                                                 const ushort_t* __restrict__ kfr,
                                                 const ushort_t* __restrict__ vfr,
                                                 const float* __restrict__ sp,
                                                 const float* __restrict__ scale_p,
                                                 ushort_t* __restrict__ pob,
                                                 float* __restrict__ pml) {
    __shared__ __align__(16) float bias_s[32][260];       // 33.3 KB
    __shared__ __align__(16) ushort_t p_s[4][2][16][72];  // 18.4 KB

    const int t = threadIdx.x;
    const int h = t >> 6;  // wave = head
    const int lane = t & 63, l15 = lane & 15, quad = lane >> 4;
    const int qt = blockIdx.x & 255;
    const int half = blockIdx.x >> 8;
    const int q0 = qt * 32;
    const int k0 = half * 4096;
    const float scale2 = scale_p[0] * 1.4426950408889634f;  // log2e folded

    // bias staging role: thread t covers sp row q0+(t>>3), col lanes (t&7)*4 (+32k)
    const int brow = t >> 3, bcol = (t & 7) * 4;
    const float* spb = sp + (size_t)(q0 + brow) * NROWS + k0 + bcol;

    // loop-invariant Q^T fragments (pre-scaled)
    bf16x8 bq[2];
#pragma unroll
    for (int qq = 0; qq < 2; ++qq)
        bq[qq] = *(const bf16x8*)(qfr + ((((size_t)(q0 >> 4) + qq) * 4 + h) * 4 + quad) * 128 + l15 * 8);

    // K/V fragment pipeline (1 tile ahead)
    bf16x8 af[4], vf[2][2];
#pragma unroll
    for (int c = 0; c < 4; ++c)
        af[c] = *(const bf16x8*)(kfr + ((((size_t)(k0 >> 4) + c) * 4 + h) * 4 + quad) * 128 + l15 * 8);
#pragma unroll
    for (int dt = 0; dt < 2; ++dt)
#pragma unroll
        for (int kc = 0; kc < 2; ++kc)
            vf[dt][kc] = *(const bf16x8*)(vfr + (((((size_t)(k0 >> 5) + kc) * 4 + h) * 2 + dt) * 4 + quad) * 128 + l15 * 8);

    // round 0 prologue: fetch + stage
    f32x4 breg[8];
#pragma unroll
    for (int k = 0; k < 8; ++k)
        breg[k] = __builtin_nontemporal_load((const f32x4*)(spb + k * 32));
#pragma unroll
    for (int k = 0; k < 8; ++k) {
        f32x4 cv = {bias_of16(breg[k][0], scale2), bias_of16(breg[k][1], scale2),
                    bias_of16(breg[k][2], scale2), bias_of16(breg[k][3], scale2)};
        *(f32x4*)&bias_s[brow][k * 32 + bcol] = cv;
    }
    __syncthreads();

    f32x4 oacc[2][2] = {};
    float l[2] = {0.f, 0.f};

    for (int rnd = 0; rnd < 16; ++rnd) {
        // fetch next round's 32x256 super-tile (1KB/row contiguous, NT)
        if (rnd < 15) {
#pragma unroll
            for (int k = 0; k < 8; ++k)
                breg[k] = __builtin_nontemporal_load((const f32x4*)(spb + (rnd + 1) * 256 + k * 32));
        }
#pragma unroll
        for (int j = 0; j < 4; ++j) {
            const int it = rnd * 4 + j;
            // C-init from staged (bias - 16)
            f32x4 sacc[4][2];
#pragma unroll
            for (int c = 0; c < 4; ++c)
#pragma unroll
                for (int qq = 0; qq < 2; ++qq)
                    sacc[c][qq] = *(const f32x4*)&bias_s[qq * 16 + l15][j * 64 + c * 16 + quad * 4];
            // QK^T (log2-domain scores, pre-shifted by -16)
#pragma unroll
            for (int c = 0; c < 4; ++c)
#pragma unroll
                for (int qq = 0; qq < 2; ++qq)
                    sacc[c][qq] = __builtin_amdgcn_mfma_f32_16x16x32_bf16(af[c], bq[qq], sacc[c][qq], 0, 0, 0);
            // prefetch next K fragments
            if (it < 63) {
                size_t rtk = (size_t)(k0 >> 4) + (it + 1) * 4;
#pragma unroll
                for (int c = 0; c < 4; ++c)
                    af[c] = *(const bf16x8*)(kfr + (((rtk + c) * 4 + h) * 4 + quad) * 128 + l15 * 8);
            }
            // p = exp2(s); accumulate l per-lane (no max, no rescale, no shfl)
#pragma unroll
            for (int qq = 0; qq < 2; ++qq) {
                float lsum = 0.f;
#pragma unroll
                for (int c = 0; c < 4; ++c)
#pragma unroll
                    for (int r = 0; r < 4; ++r) {
                        float p = exp2_fast(sacc[c][qq][r]);
                        sacc[c][qq][r] = p;
                        lsum += p;
                    }
                l[qq] += lsum;
            }
            // write P (truncating bf16 pack; p in (0, ~0.35])
#pragma unroll
            for (int qq = 0; qq < 2; ++qq)
#pragma unroll
                for (int c = 0; c < 4; ++c) {
                    unsigned b0 = __float_as_uint(sacc[c][qq][0]);
                    unsigned b1 = __float_as_uint(sacc[c][qq][1]);
                    unsigned b2 = __float_as_uint(sacc[c][qq][2]);
                    unsigned b3 = __float_as_uint(sacc[c][qq][3]);
                    uint2 pw;
                    pw.x = __builtin_amdgcn_perm(b1, b0, 0x07060302);
                    pw.y = __builtin_amdgcn_perm(b3, b2, 0x07060302);
                    *(uint2*)&p_s[h][qq][l15][c * 16 + quad * 4] = pw;
                }
            asm volatile("s_waitcnt lgkmcnt(0)" ::: "memory");  // same-wave P RAW
            bf16x8 pf[2][2];
#pragma unroll
            for (int qq = 0; qq < 2; ++qq)
#pragma unroll
                for (int kc = 0; kc < 2; ++kc)
                    pf[qq][kc] = *(const bf16x8*)&p_s[h][qq][l15][kc * 32 + quad * 8];
            // PV: O^T += V^T . P^T
#pragma unroll
            for (int dt = 0; dt < 2; ++dt)
#pragma unroll
                for (int qq = 0; qq < 2; ++qq) {
                    oacc[dt][qq] = __builtin_amdgcn_mfma_f32_16x16x32_bf16(vf[dt][0], pf[qq][0], oacc[dt][qq], 0, 0, 0);
                    oacc[dt][qq] = __builtin_amdgcn_mfma_f32_16x16x32_bf16(vf[dt][1], pf[qq][1], oacc[dt][qq], 0, 0, 0);
                }
            // prefetch next V fragments
            if (it < 63) {
                size_t kb = (size_t)(k0 >> 5) + (it + 1) * 2;
#pragma unroll
                for (int dt = 0; dt < 2; ++dt)
#pragma unroll
                    for (int kc = 0; kc < 2; ++kc)
                        vf[dt][kc] = *(const bf16x8*)(vfr + ((((kb + kc) * 4 + h) * 2 + dt) * 4 + quad) * 128 + l15 * 8);
            }
        }
        // stage next round from regs (single buffer: barrier, overwrite, barrier)
        if (rnd < 15) {
            __syncthreads();
#pragma unroll
            for (int k = 0; k < 8; ++k) {
                f32x4 cv = {bias_of16(breg[k][0], scale2), bias_of16(breg[k][1], scale2),
                            bias_of16(breg[k][2], scale2), bias_of16(breg[k][3], scale2)};
                *(f32x4*)&bias_s[brow][k * 32 + bcol] = cv;
            }
            __syncthreads();
        }
    }

    // epilogue: reduce l across quads; store partials
    // pob layout: [qtile][h][half][dt][quad][l15][4] -> lane 8B, wave 512B contig
#pragma unroll
    for (int qq = 0; qq < 2; ++qq) {
        float lt = l[qq];
        lt += __shfl_xor(lt, 16, 64);
        lt += __shfl_xor(lt, 32, 64);
        int qtile = qt * 2 + qq;
        if (quad == 0)
            pml[((size_t)(q0 + qq * 16 + l15) * 4 + h) * 2 + half] = lt;
#pragma unroll
        for (int dt = 0; dt < 2; ++dt) {
            short4v pk = {f2bf(oacc[dt][qq][0]), f2bf(oacc[dt][qq][1]),
                          f2bf(oacc[dt][qq][2]), f2bf(oacc[dt][qq][3])};
            *(short4v*)&pob[(((((size_t)qtile * 4 + h) * 2 + half) * 2 + dt) * 256)
                            + quad * 64 + l15 * 4] = pk;
        }
    }
}

// ---------- K3: epilogue (2-way partial merge + out_proj -> relu+residual -> W_out -> log_softmax) ----------
__global__ __launch_bounds__(256) void k_epi(const ushort_t* __restrict__ hbf,
                                             const ushort_t* __restrict__ pob,
                                             const float* __restrict__ pml,
                                             const ushort_t* __restrict__ wofr,
                                             const float* __restrict__ bo,
                                             const ushort_t* __restrict__ woutfr,
                                             const float* __restrict__ bout,
                                             float* __restrict__ out) {
    __shared__ __align__(16) ushort_t hr_s[16][136];
    const int w = threadIdx.x >> 6, lane = threadIdx.x & 63;
    const int l15 = lane & 15, quad = lane >> 4;
    const int rt = blockIdx.x;
    const int r0 = rt * 16;

    // phase A: merge 2 half-partials (plain sum) -> A-frags;
    // o2 = O @ Wo^T + bo -> relu -> +h -> hr_s (bf16)
    {
        bf16x8 af[4], bfr[2][4];
#pragma unroll
        for (int kf = 0; kf < 4; ++kf) {
            float2 lv = *(const float2*)(pml + ((size_t)(r0 + l15) * 4 + kf) * 2);
            float linv = 1.f / (lv.x + lv.y);
            float acc[8] = {0.f, 0.f, 0.f, 0.f, 0.f, 0.f, 0.f, 0.f};
#pragma unroll
            for (int j = 0; j < 2; ++j) {
                size_t base = ((((size_t)rt * 4 + kf) * 2 + j) * 2 + (quad >> 1)) * 256
                              + (quad & 1) * 128 + l15 * 4;
                short4v v0 = *(const short4v*)(pob + base);
                short4v v1 = *(const short4v*)(pob + base + 64);
#pragma unroll
                for (int e = 0; e < 4; ++e) {
                    acc[e] += bf2f((ushort_t)v0[e]);
                    acc[4 + e] += bf2f((ushort_t)v1[e]);
                }
            }
            bf16x8 a;
#pragma unroll
            for (int e = 0; e < 8; ++e) a[e] = f2bf(acc[e] * linv);
            af[kf] = a;
        }
#pragma unroll
        for (int nt = 0; nt < 2; ++nt)
#pragma unroll
            for (int kf = 0; kf < 4; ++kf)
                bfr[nt][kf] = *(const bf16x8*)(wofr + (((size_t)(w * 2 + nt) * 4 + kf) * 4 + quad) * 128 + l15 * 8);
#pragma unroll
        for (int nt = 0; nt < 2; ++nt) {
            float bias = bo[w * 32 + nt * 16 + l15];
            f32x4 c = {bias, bias, bias, bias};
#pragma unroll
            for (int kf = 0; kf < 4; ++kf)
                c = __builtin_amdgcn_mfma_f32_16x16x32_bf16(af[kf], bfr[nt][kf], c, 0, 0, 0);
            int col = w * 32 + nt * 16 + l15;
#pragma unroll
            for (int r = 0; r < 4; ++r) {
                int row = quad * 4 + r;
                float val = fmaxf(c[r], 0.f) + bf2f(hbf[(size_t)(r0 + row) * 128 + col]);
                hr_s[row][col] = (ushort_t)f2bf(val);
            }
        }
    }
    __syncthreads();
    // phase B (wave 0): logits^T = Wout . hr^T ; in-lane log_softmax per row
    if (w == 0) {
        f32x4 c[3];
#pragma unroll
        for (int mt = 0; mt < 3; ++mt)
#pragma unroll
            for (int r = 0; r < 4; ++r) {
                int oc = mt * 16 + quad * 4 + r;
                c[mt][r] = (oc < OUTC) ? bout[oc] : 0.f;
            }
#pragma unroll
        for (int kf = 0; kf < 4; ++kf) {
            bf16x8 bfrag = *(const bf16x8*)&hr_s[l15][kf * 32 + quad * 8];
#pragma unroll
            for (int mt = 0; mt < 3; ++mt) {
                bf16x8 afr = *(const bf16x8*)(woutfr + (((size_t)mt * 4 + kf) * 4 + quad) * 128 + l15 * 8);
                c[mt] = __builtin_amdgcn_mfma_f32_16x16x32_bf16(afr, bfrag, c[mt], 0, 0, 0);
            }
        }
        float mx = -1e30f;
#pragma unroll
        for (int mt = 0; mt < 3; ++mt)
#pragma unroll
            for (int r = 0; r < 4; ++r) {
                int oc = mt * 16 + quad * 4 + r;
                if (oc >= OUTC) c[mt][r] = -1e30f;
                mx = fmaxf(mx, c[mt][r]);
            }
        mx = fmaxf(mx, __shfl_xor(mx, 16, 64));
        mx = fmaxf(mx, __shfl_xor(mx, 32, 64));
        float ssum = 0.f;
#pragma unroll
        for (int mt = 0; mt < 3; ++mt)
#pragma unroll
            for (int r = 0; r < 4; ++r) ssum += __expf(c[mt][r] - mx);
        ssum += __shfl_xor(ssum, 16, 64);
        ssum += __shfl_xor(ssum, 32, 64);
        float lse = __logf(ssum) + mx;
        int row = r0 + l15;
#pragma unroll
        for (int mt = 0; mt < 2; ++mt) {
            float4 st = make_float4(c[mt][0] - lse, c[mt][1] - lse, c[mt][2] - lse, c[mt][3] - lse);
            *(float4*)(out + (size_t)row * OUTC + mt * 16 + quad * 4) = st;
        }
        if (quad < 2) {
            float4 st = make_float4(c[2][0] - lse, c[2][1] - lse, c[2][2] - lse, c[2][3] - lse);
            *(float4*)(out + (size_t)row * OUTC + 32 + quad * 4) = st;
        }
    }
}

extern "C" void kernel_launch(void* const* d_in, const int* in_sizes, int n_in,
                              void* d_out, int out_size, void* d_ws, size_t ws_size,
                              hipStream_t stream) {
    const float* x          = (const float*)d_in[0];
    // d_in[1] = pos_enc (unused in forward, faithful to reference)
    const float* sp         = (const float*)d_in[2];
    const float* W_in       = (const float*)d_in[3];
    const float* b_in       = (const float*)d_in[4];
    const float* in_proj_w  = (const float*)d_in[5];
    const float* in_proj_b  = (const float*)d_in[6];
    const float* out_proj_w = (const float*)d_in[7];
    const float* out_proj_b = (const float*)d_in[8];
    const float* W_out      = (const float*)d_in[9];
    const float* b_out      = (const float*)d_in[10];
    const float* scale      = (const float*)d_in[11];

    float*    pml    = (float*)d_ws;                          // 8192*4*2 f32 = 256 KiB
    ushort_t* pob    = (ushort_t*)(pml + (size_t)NROWS * 8);  // 4 MiB bf16 partial O
    ushort_t* xfr    = pob + (size_t)NROWS * 256;
    ushort_t* qfr    = xfr + (size_t)NROWS * 128;
    ushort_t* kfr    = qfr + (size_t)NROWS * 128;
    ushort_t* vfr    = kfr + (size_t)NROWS * 128;
    ushort_t* hbf    = vfr + (size_t)NROWS * 128;
    ushort_t* wifr   = hbf + (size_t)NROWS * 128;
    ushort_t* wpfr   = wifr + 128 * 128;
    ushort_t* wofr   = wpfr + 384 * 128;
    ushort_t* woutfr = wofr + 128 * 128;                      // 48*128 (zero-padded)
    float*    out    = (float*)d_out;

    hipLaunchKernelGGL(k_prep, dim3(555), dim3(256), 0, stream,
                       x, W_in, in_proj_w, out_proj_w, W_out, xfr, wifr, wpfr, wofr, woutfr);
    hipLaunchKernelGGL(k_qkv_fused, dim3(NROWS / 16), dim3(256), 0, stream,
                       xfr, wifr, b_in, wpfr, in_proj_b, hbf, qfr, kfr, vfr);
    hipLaunchKernelGGL(k_attn, dim3(256 * 2), dim3(256), 0, stream,
                       qfr, kfr, vfr, sp, scale, pob, pml);
    hipLaunchKernelGGL(k_epi, dim3(NROWS / 16), dim3(256), 0, stream,
                       hbf, pob, pml, wofr, out_proj_b, woutfr, b_out, out);
}